// Round 5
// baseline (1900.343 us; speedup 1.0000x reference)
//
#include <hip/hip_runtime.h>
#include <hip/hip_bf16.h>

// Problem constants (from reference)
#define NU 100000
#define NI 50000
#define NE 1000000
#define NP 500000
// D_IN = D_HID = 128, D_OUT = 64

// ---------------- CSR build ----------------

__global__ void hist_kernel(const int* __restrict__ dst, int* __restrict__ deg, int E) {
    int e = blockIdx.x * blockDim.x + threadIdx.x;
    if (e < E) atomicAdd(&deg[dst[e]], 1);
}

__global__ void scan_local_kernel(const int* __restrict__ in, int* __restrict__ out,
                                  int* __restrict__ bsum, int n) {
    __shared__ int s[1024];
    int i = blockIdx.x * 1024 + threadIdx.x;
    int v = (i < n) ? in[i] : 0;
    s[threadIdx.x] = v;
    __syncthreads();
    for (int off = 1; off < 1024; off <<= 1) {
        int t = (threadIdx.x >= off) ? s[threadIdx.x - off] : 0;
        __syncthreads();
        s[threadIdx.x] += t;
        __syncthreads();
    }
    if (i < n) out[i] = s[threadIdx.x] - v;   // exclusive within block
    if (threadIdx.x == 1023) bsum[blockIdx.x] = s[1023];
}

__global__ void scan_bsum_kernel(int* bsum, int nb) {
    __shared__ int s[1024];
    int v = (threadIdx.x < nb) ? bsum[threadIdx.x] : 0;
    s[threadIdx.x] = v;
    __syncthreads();
    for (int off = 1; off < 1024; off <<= 1) {
        int t = (threadIdx.x >= off) ? s[threadIdx.x - off] : 0;
        __syncthreads();
        s[threadIdx.x] += t;
        __syncthreads();
    }
    if (threadIdx.x < nb) bsum[threadIdx.x] = s[threadIdx.x] - v;  // exclusive
}

__global__ void scan_finalize_kernel(int* __restrict__ rs, const int* __restrict__ bsum,
                                     int* __restrict__ cursor, int n, int E) {
    int i = blockIdx.x * 1024 + threadIdx.x;
    if (i < n) {
        int v = rs[i] + bsum[blockIdx.x];
        rs[i] = v;
        cursor[i] = v;
    }
    if (i == 0) rs[n] = E;
}

__global__ void fill_kernel(const int* __restrict__ src, const int* __restrict__ dst,
                            int* cursor, int* __restrict__ csr, int E) {
    int e = blockIdx.x * blockDim.x + threadIdx.x;
    if (e < E) {
        int p = atomicAdd(&cursor[dst[e]], 1);
        csr[p] = src[e];
    }
}

// ---------------- mean aggregation (CSR, atomic-free) ----------------
// 2 dst nodes per 256-thread block; thread j owns feature dim j (128 dims).
__global__ __launch_bounds__(256) void agg_kernel(const float* __restrict__ hsrc,
                                                  const int* __restrict__ rs,
                                                  const int* __restrict__ csr,
                                                  float* __restrict__ out, int T) {
    int t = blockIdx.x * 2 + (threadIdx.x >> 7);
    int j = threadIdx.x & 127;
    if (t >= T) return;
    int e0 = rs[t], e1 = rs[t + 1];
    float acc = 0.f;
    for (int e = e0; e < e1; ++e) {
        int s = csr[e];
        acc += hsrc[(size_t)s * 128 + j];
    }
    float inv = (e1 > e0) ? 1.f / (float)(e1 - e0) : 0.f;
    out[(size_t)t * 128 + j] = acc * inv;
}

// ---------------- conv: z = hn@Wn + bn + hd@Ws + bs; relu; row L2-norm ----------------
// Tile: 32 rows x DOUT cols per 256-thread block. A = [hn | hd] staged in LDS (K=256).
template <int DOUT>
__global__ __launch_bounds__(256) void conv_kernel(const float* __restrict__ hn,
                                                   const float* __restrict__ hd,
                                                   const float* __restrict__ Wn,
                                                   const float* __restrict__ bn,
                                                   const float* __restrict__ Ws,
                                                   const float* __restrict__ bs,
                                                   float* __restrict__ out, int T) {
    constexpr int TM = 32;
    constexpr int GROUP = DOUT / 4;            // threads cooperating on one row set
    constexpr int RPT = (TM * GROUP) / 256;    // rows per thread (4 for 128, 2 for 64)
    __shared__ float A[TM][264];               // 264: 16B-aligned rows, bank-spread

    const int tid = threadIdx.x;
    const int t0 = blockIdx.x * TM;

    // stage [hn | hd] tile: 32 rows x 256 floats = 2048 float4, 8 per thread
    #pragma unroll
    for (int i = 0; i < 8; ++i) {
        int lin = i * 256 + tid;
        int row = lin >> 6;
        int q   = lin & 63;
        int t   = t0 + row;
        float4 v = {0.f, 0.f, 0.f, 0.f};
        if (t < T) {
            v = (q < 32) ? *(const float4*)&hn[(size_t)t * 128 + (q << 2)]
                         : *(const float4*)&hd[(size_t)t * 128 + ((q - 32) << 2)];
        }
        *(float4*)&A[row][q << 2] = v;
    }
    __syncthreads();

    const int cg = tid % GROUP, rg = tid / GROUP;
    const int c0 = cg * 4, r0 = rg * RPT;

    float acc[RPT][4] = {};
    #pragma unroll
    for (int half = 0; half < 2; ++half) {
        const float* __restrict__ W = half ? Ws : Wn;
        const int kb = half * 128;
        for (int k = 0; k < 128; k += 4) {
            float4 w0 = *(const float4*)&W[(size_t)(k + 0) * DOUT + c0];
            float4 w1 = *(const float4*)&W[(size_t)(k + 1) * DOUT + c0];
            float4 w2 = *(const float4*)&W[(size_t)(k + 2) * DOUT + c0];
            float4 w3 = *(const float4*)&W[(size_t)(k + 3) * DOUT + c0];
            #pragma unroll
            for (int r = 0; r < RPT; ++r) {
                float4 a = *(const float4*)&A[r0 + r][kb + k];
                acc[r][0] = fmaf(a.x, w0.x, acc[r][0]);
                acc[r][1] = fmaf(a.x, w0.y, acc[r][1]);
                acc[r][2] = fmaf(a.x, w0.z, acc[r][2]);
                acc[r][3] = fmaf(a.x, w0.w, acc[r][3]);
                acc[r][0] = fmaf(a.y, w1.x, acc[r][0]);
                acc[r][1] = fmaf(a.y, w1.y, acc[r][1]);
                acc[r][2] = fmaf(a.y, w1.z, acc[r][2]);
                acc[r][3] = fmaf(a.y, w1.w, acc[r][3]);
                acc[r][0] = fmaf(a.z, w2.x, acc[r][0]);
                acc[r][1] = fmaf(a.z, w2.y, acc[r][1]);
                acc[r][2] = fmaf(a.z, w2.z, acc[r][2]);
                acc[r][3] = fmaf(a.z, w2.w, acc[r][3]);
                acc[r][0] = fmaf(a.w, w3.x, acc[r][0]);
                acc[r][1] = fmaf(a.w, w3.y, acc[r][1]);
                acc[r][2] = fmaf(a.w, w3.z, acc[r][2]);
                acc[r][3] = fmaf(a.w, w3.w, acc[r][3]);
            }
        }
    }

    float bias[4];
    #pragma unroll
    for (int c = 0; c < 4; ++c) bias[c] = bn[c0 + c] + bs[c0 + c];

    #pragma unroll
    for (int r = 0; r < RPT; ++r) {
        float n2 = 0.f;
        #pragma unroll
        for (int c = 0; c < 4; ++c) {
            float z = fmaxf(acc[r][c] + bias[c], 0.f);
            acc[r][c] = z;
            n2 = fmaf(z, z, n2);
        }
        #pragma unroll
        for (int m = 1; m < GROUP; m <<= 1) n2 += __shfl_xor(n2, m);
        float inv = 1.f / fmaxf(sqrtf(n2), 1e-12f);
        int t = t0 + r0 + r;
        if (t < T) {
            float4 o = {acc[r][0] * inv, acc[r][1] * inv, acc[r][2] * inv, acc[r][3] * inv};
            *(float4*)&out[(size_t)t * DOUT + c0] = o;
        }
    }
}

// ---------------- cosine scores ----------------
// 16 lanes per pair (16 x float4 = 64 dims)
__global__ __launch_bounds__(256) void score_kernel(const float* __restrict__ hu,
                                                    const float* __restrict__ hi,
                                                    const int* __restrict__ pu,
                                                    const int* __restrict__ pi,
                                                    float* __restrict__ out, int P) {
    int g = threadIdx.x >> 4, l = threadIdx.x & 15;
    int p = blockIdx.x * 16 + g;
    if (p >= P) return;
    int u = pu[p], it = pi[p];
    float4 a = *(const float4*)&hu[(size_t)u * 64 + (l << 2)];
    float4 b = *(const float4*)&hi[(size_t)it * 64 + (l << 2)];
    float d  = a.x * b.x + a.y * b.y + a.z * b.z + a.w * b.w;
    float na = a.x * a.x + a.y * a.y + a.z * a.z + a.w * a.w;
    float nb = b.x * b.x + b.y * b.y + b.z * b.z + b.w * b.w;
    #pragma unroll
    for (int m = 1; m < 16; m <<= 1) {
        d  += __shfl_xor(d, m);
        na += __shfl_xor(na, m);
        nb += __shfl_xor(nb, m);
    }
    if (l == 0) out[p] = d / (fmaxf(sqrtf(na), 1e-12f) * fmaxf(sqrtf(nb), 1e-12f));
}

// ---------------- host ----------------

extern "C" void kernel_launch(void* const* d_in, const int* in_sizes, int n_in,
                              void* d_out, int out_size, void* d_ws, size_t ws_size,
                              hipStream_t stream) {
    const float* h_user = (const float*)d_in[0];
    const float* h_item = (const float*)d_in[1];
    const float* Wn01   = (const float*)d_in[2];
    const float* bn01   = (const float*)d_in[3];
    const float* Ws01   = (const float*)d_in[4];
    const float* bs01   = (const float*)d_in[5];
    const float* Wn2    = (const float*)d_in[6];
    const float* bn2    = (const float*)d_in[7];
    const float* Ws2    = (const float*)d_in[8];
    const float* bs2    = (const float*)d_in[9];
    const int* u2i_src  = (const int*)d_in[10];
    const int* u2i_dst  = (const int*)d_in[11];
    const int* i2u_src  = (const int*)d_in[12];
    const int* i2u_dst  = (const int*)d_in[13];
    const int* pos_u    = (const int*)d_in[14];
    const int* pos_i    = (const int*)d_in[15];
    const int* neg_u    = (const int*)d_in[16];
    const int* neg_i    = (const int*)d_in[17];

    float* out = (float*)d_out;
    float* out_hu = out;                       // [NU,64]
    float* out_hi = out + (size_t)NU * 64;     // [NI,64]
    float* out_pos = out + (size_t)NU * 64 + (size_t)NI * 64;
    float* out_neg = out_pos + NP;

    // workspace layout
    char* ws = (char*)d_ws;
    size_t off = 0;
    auto alloc = [&](size_t bytes) -> void* {
        void* p = ws + off;
        off = (off + bytes + 255) & ~(size_t)255;
        return p;
    };
    float* hu_b = (float*)alloc((size_t)NU * 128 * 4);
    float* hi_b = (float*)alloc((size_t)NI * 128 * 4);
    float* hu_a = (float*)alloc((size_t)NU * 128 * 4);
    float* hi_a = (float*)alloc((size_t)NI * 128 * 4);
    float* agg  = (float*)alloc((size_t)NU * 128 * 4);
    int* csr_u2i = (int*)alloc((size_t)NE * 4);
    int* csr_i2u = (int*)alloc((size_t)NE * 4);
    int* rs_i   = (int*)alloc((size_t)(NI + 1) * 4);
    int* rs_u   = (int*)alloc((size_t)(NU + 1) * 4);
    int* deg    = (int*)alloc((size_t)NU * 4);
    int* cursor = (int*)alloc((size_t)NU * 4);
    int* bsum   = (int*)alloc(1024 * 4);
    (void)ws_size; (void)in_sizes; (void)n_in; (void)out_size;

    const int eblocks = (NE + 255) / 256;

    // ---- CSR for u2i (dst = items) ----
    {
        hipMemsetAsync(deg, 0, (size_t)NI * 4, stream);
        hist_kernel<<<eblocks, 256, 0, stream>>>(u2i_dst, deg, NE);
        int nb = (NI + 1023) / 1024;
        scan_local_kernel<<<nb, 1024, 0, stream>>>(deg, rs_i, bsum, NI);
        scan_bsum_kernel<<<1, 1024, 0, stream>>>(bsum, nb);
        scan_finalize_kernel<<<nb, 1024, 0, stream>>>(rs_i, bsum, cursor, NI, NE);
        fill_kernel<<<eblocks, 256, 0, stream>>>(u2i_src, u2i_dst, cursor, csr_u2i, NE);
    }
    // ---- CSR for i2u (dst = users) ----
    {
        hipMemsetAsync(deg, 0, (size_t)NU * 4, stream);
        hist_kernel<<<eblocks, 256, 0, stream>>>(i2u_dst, deg, NE);
        int nb = (NU + 1023) / 1024;
        scan_local_kernel<<<nb, 1024, 0, stream>>>(deg, rs_u, bsum, NU);
        scan_bsum_kernel<<<1, 1024, 0, stream>>>(bsum, nb);
        scan_finalize_kernel<<<nb, 1024, 0, stream>>>(rs_u, bsum, cursor, NU, NE);
        fill_kernel<<<eblocks, 256, 0, stream>>>(i2u_src, i2u_dst, cursor, csr_i2u, NE);
    }

    const int gi = (NI + 1) / 2, gu = (NU + 1) / 2;          // agg grids
    const int ci = (NI + 31) / 32, cu = (NU + 31) / 32;      // conv grids

    // ---- layer 0 (reads inputs) ----
    agg_kernel<<<gi, 256, 0, stream>>>(h_user, rs_i, csr_u2i, agg, NI);
    conv_kernel<128><<<ci, 256, 0, stream>>>(agg, h_item, Wn01 + 0, bn01 + 0,
                                             Ws01 + 0, bs01 + 0, hi_b, NI);
    agg_kernel<<<gu, 256, 0, stream>>>(h_item, rs_u, csr_i2u, agg, NU);
    conv_kernel<128><<<cu, 256, 0, stream>>>(agg, h_user, Wn01 + 16384, bn01 + 128,
                                             Ws01 + 16384, bs01 + 128, hu_b, NU);
    // ---- layer 1 ----
    agg_kernel<<<gi, 256, 0, stream>>>(hu_b, rs_i, csr_u2i, agg, NI);
    conv_kernel<128><<<ci, 256, 0, stream>>>(agg, hi_b, Wn01 + 32768, bn01 + 256,
                                             Ws01 + 32768, bs01 + 256, hi_a, NI);
    agg_kernel<<<gu, 256, 0, stream>>>(hi_b, rs_u, csr_i2u, agg, NU);
    conv_kernel<128><<<cu, 256, 0, stream>>>(agg, hu_b, Wn01 + 49152, bn01 + 384,
                                             Ws01 + 49152, bs01 + 384, hu_a, NU);
    // ---- layer 2 (writes d_out embeddings) ----
    agg_kernel<<<gi, 256, 0, stream>>>(hu_a, rs_i, csr_u2i, agg, NI);
    conv_kernel<64><<<ci, 256, 0, stream>>>(agg, hi_a, Wn2 + 0, bn2 + 0,
                                            Ws2 + 0, bs2 + 0, out_hi, NI);
    agg_kernel<<<gu, 256, 0, stream>>>(hi_a, rs_u, csr_i2u, agg, NU);
    conv_kernel<64><<<cu, 256, 0, stream>>>(agg, hu_a, Wn2 + 8192, bn2 + 64,
                                            Ws2 + 8192, bs2 + 64, out_hu, NU);

    // ---- cosine scores ----
    const int pblocks = (NP + 15) / 16;
    score_kernel<<<pblocks, 256, 0, stream>>>(out_hu, out_hi, pos_u, pos_i, out_pos, NP);
    score_kernel<<<pblocks, 256, 0, stream>>>(out_hu, out_hi, neg_u, neg_i, out_neg, NP);
}

// Round 6
// 1188.578 us; speedup vs baseline: 1.5988x; 1.5988x over previous
//
#include <hip/hip_runtime.h>
#include <hip/hip_bf16.h>

// Problem constants (from reference)
#define NU 100000
#define NI 50000
#define NE 1000000
#define NP 500000
// D_IN = D_HID = 128, D_OUT = 64

typedef unsigned short u16;
typedef unsigned int u32;

static __device__ __forceinline__ u16 f2bf(float f) {
    union { float f; u32 u; } x; x.f = f;
    u32 r = x.u + 0x7fff + ((x.u >> 16) & 1);   // round-to-nearest-even
    return (u16)(r >> 16);
}
static __device__ __forceinline__ float bf2f(u16 h) {
    union { u32 u; float f; } x; x.u = ((u32)h) << 16;
    return x.f;
}

// ---------------- f32 -> bf16 table conversion ----------------
__global__ __launch_bounds__(256) void cvt_kernel(const float* __restrict__ in,
                                                  u16* __restrict__ out, int n8) {
    int i = blockIdx.x * blockDim.x + threadIdx.x;
    if (i >= n8) return;
    float4 a = ((const float4*)in)[2 * i];
    float4 b = ((const float4*)in)[2 * i + 1];
    ushort4 lo = {f2bf(a.x), f2bf(a.y), f2bf(a.z), f2bf(a.w)};
    ushort4 hi = {f2bf(b.x), f2bf(b.y), f2bf(b.z), f2bf(b.w)};
    ((ushort4*)out)[2 * i]     = lo;
    ((ushort4*)out)[2 * i + 1] = hi;
}

// ---------------- CSR build ----------------

__global__ void hist_kernel(const int* __restrict__ dst, int* __restrict__ deg, int E) {
    int e = blockIdx.x * blockDim.x + threadIdx.x;
    if (e < E) atomicAdd(&deg[dst[e]], 1);
}

__global__ void scan_local_kernel(const int* __restrict__ in, int* __restrict__ out,
                                  int* __restrict__ bsum, int n) {
    __shared__ int s[1024];
    int i = blockIdx.x * 1024 + threadIdx.x;
    int v = (i < n) ? in[i] : 0;
    s[threadIdx.x] = v;
    __syncthreads();
    for (int off = 1; off < 1024; off <<= 1) {
        int t = (threadIdx.x >= off) ? s[threadIdx.x - off] : 0;
        __syncthreads();
        s[threadIdx.x] += t;
        __syncthreads();
    }
    if (i < n) out[i] = s[threadIdx.x] - v;   // exclusive within block
    if (threadIdx.x == 1023) bsum[blockIdx.x] = s[1023];
}

__global__ void scan_bsum_kernel(int* bsum, int nb) {
    __shared__ int s[1024];
    int v = (threadIdx.x < nb) ? bsum[threadIdx.x] : 0;
    s[threadIdx.x] = v;
    __syncthreads();
    for (int off = 1; off < 1024; off <<= 1) {
        int t = (threadIdx.x >= off) ? s[threadIdx.x - off] : 0;
        __syncthreads();
        s[threadIdx.x] += t;
        __syncthreads();
    }
    if (threadIdx.x < nb) bsum[threadIdx.x] = s[threadIdx.x] - v;  // exclusive
}

__global__ void scan_finalize_kernel(int* __restrict__ rs, const int* __restrict__ bsum,
                                     int* __restrict__ cursor, int n, int E) {
    int i = blockIdx.x * 1024 + threadIdx.x;
    if (i < n) {
        int v = rs[i] + bsum[blockIdx.x];
        rs[i] = v;
        cursor[i] = v;
    }
    if (i == 0) rs[n] = E;
}

__global__ void fill_kernel(const int* __restrict__ src, const int* __restrict__ dst,
                            int* cursor, int* __restrict__ csr, int E) {
    int e = blockIdx.x * blockDim.x + threadIdx.x;
    if (e < E) {
        int p = atomicAdd(&cursor[dst[e]], 1);
        csr[p] = src[e];
    }
}

// ---------------- mean aggregation (CSR, atomic-free, bf16 tables) ----------------
// 4 dst nodes per 256-thread block; one wave per node; lane owns dims {2j,2j+1}.
__global__ __launch_bounds__(256) void agg_kernel(const u16* __restrict__ hsrc,
                                                  const int* __restrict__ rs,
                                                  const int* __restrict__ csr,
                                                  u16* __restrict__ out, int T) {
    int t = blockIdx.x * 4 + (threadIdx.x >> 6);
    int j = (threadIdx.x & 63) << 1;
    if (t >= T) return;
    int e0 = rs[t], e1 = rs[t + 1];
    float a0 = 0.f, a1 = 0.f;
    int e = e0;
    for (; e + 1 < e1; e += 2) {
        int s0 = csr[e], s1 = csr[e + 1];
        ushort2 v0 = *(const ushort2*)&hsrc[(size_t)s0 * 128 + j];
        ushort2 v1 = *(const ushort2*)&hsrc[(size_t)s1 * 128 + j];
        a0 += bf2f(v0.x) + bf2f(v1.x);
        a1 += bf2f(v0.y) + bf2f(v1.y);
    }
    if (e < e1) {
        int s0 = csr[e];
        ushort2 v0 = *(const ushort2*)&hsrc[(size_t)s0 * 128 + j];
        a0 += bf2f(v0.x);
        a1 += bf2f(v0.y);
    }
    float inv = (e1 > e0) ? 1.f / (float)(e1 - e0) : 0.f;
    ushort2 o = {f2bf(a0 * inv), f2bf(a1 * inv)};
    *(ushort2*)&out[(size_t)t * 128 + j] = o;
}

// ---------------- conv: z = hn@Wn + bn + hd@Ws + bs; relu; row L2-norm ----------------
// bf16 inputs, f32 compute in LDS/regs, bf16 output (+optional f32 for d_out).
template <int DOUT, bool WRITE_F32>
__global__ __launch_bounds__(256) void conv_kernel(const u16* __restrict__ hn,
                                                   const u16* __restrict__ hd,
                                                   const float* __restrict__ Wn,
                                                   const float* __restrict__ bn,
                                                   const float* __restrict__ Ws,
                                                   const float* __restrict__ bs,
                                                   float* __restrict__ outf,
                                                   u16* __restrict__ outb, int T) {
    constexpr int TM = 32;
    constexpr int GROUP = DOUT / 4;            // threads cooperating on one row set
    constexpr int RPT = (TM * GROUP) / 256;    // rows per thread (4 for 128, 2 for 64)
    __shared__ float A[TM][264];               // 264: 16B-aligned rows, bank-spread

    const int tid = threadIdx.x;
    const int t0 = blockIdx.x * TM;

    // stage [hn | hd] tile: 32 rows x 256 dims (bf16 -> f32), 2048 x 4-dim slots
    #pragma unroll
    for (int i = 0; i < 8; ++i) {
        int lin = i * 256 + tid;
        int row = lin >> 6;
        int q   = lin & 63;
        int t   = t0 + row;
        float4 v = {0.f, 0.f, 0.f, 0.f};
        if (t < T) {
            const u16* src = (q < 32) ? &hn[(size_t)t * 128 + (q << 2)]
                                      : &hd[(size_t)t * 128 + ((q - 32) << 2)];
            ushort4 u = *(const ushort4*)src;
            v.x = bf2f(u.x); v.y = bf2f(u.y); v.z = bf2f(u.z); v.w = bf2f(u.w);
        }
        *(float4*)&A[row][q << 2] = v;
    }
    __syncthreads();

    const int cg = tid % GROUP, rg = tid / GROUP;
    const int c0 = cg * 4, r0 = rg * RPT;

    float acc[RPT][4] = {};
    #pragma unroll
    for (int half = 0; half < 2; ++half) {
        const float* __restrict__ W = half ? Ws : Wn;
        const int kb = half * 128;
        for (int k = 0; k < 128; k += 4) {
            float4 w0 = *(const float4*)&W[(size_t)(k + 0) * DOUT + c0];
            float4 w1 = *(const float4*)&W[(size_t)(k + 1) * DOUT + c0];
            float4 w2 = *(const float4*)&W[(size_t)(k + 2) * DOUT + c0];
            float4 w3 = *(const float4*)&W[(size_t)(k + 3) * DOUT + c0];
            #pragma unroll
            for (int r = 0; r < RPT; ++r) {
                float4 a = *(const float4*)&A[r0 + r][kb + k];
                acc[r][0] = fmaf(a.x, w0.x, acc[r][0]);
                acc[r][1] = fmaf(a.x, w0.y, acc[r][1]);
                acc[r][2] = fmaf(a.x, w0.z, acc[r][2]);
                acc[r][3] = fmaf(a.x, w0.w, acc[r][3]);
                acc[r][0] = fmaf(a.y, w1.x, acc[r][0]);
                acc[r][1] = fmaf(a.y, w1.y, acc[r][1]);
                acc[r][2] = fmaf(a.y, w1.z, acc[r][2]);
                acc[r][3] = fmaf(a.y, w1.w, acc[r][3]);
                acc[r][0] = fmaf(a.z, w2.x, acc[r][0]);
                acc[r][1] = fmaf(a.z, w2.y, acc[r][1]);
                acc[r][2] = fmaf(a.z, w2.z, acc[r][2]);
                acc[r][3] = fmaf(a.z, w2.w, acc[r][3]);
                acc[r][0] = fmaf(a.w, w3.x, acc[r][0]);
                acc[r][1] = fmaf(a.w, w3.y, acc[r][1]);
                acc[r][2] = fmaf(a.w, w3.z, acc[r][2]);
                acc[r][3] = fmaf(a.w, w3.w, acc[r][3]);
            }
        }
    }

    float bias[4];
    #pragma unroll
    for (int c = 0; c < 4; ++c) bias[c] = bn[c0 + c] + bs[c0 + c];

    #pragma unroll
    for (int r = 0; r < RPT; ++r) {
        float n2 = 0.f;
        #pragma unroll
        for (int c = 0; c < 4; ++c) {
            float z = fmaxf(acc[r][c] + bias[c], 0.f);
            acc[r][c] = z;
            n2 = fmaf(z, z, n2);
        }
        #pragma unroll
        for (int m = 1; m < GROUP; m <<= 1) n2 += __shfl_xor(n2, m);
        float inv = 1.f / fmaxf(sqrtf(n2), 1e-12f);
        int t = t0 + r0 + r;
        if (t < T) {
            float4 o = {acc[r][0] * inv, acc[r][1] * inv, acc[r][2] * inv, acc[r][3] * inv};
            ushort4 ob = {f2bf(o.x), f2bf(o.y), f2bf(o.z), f2bf(o.w)};
            *(ushort4*)&outb[(size_t)t * DOUT + c0] = ob;
            if (WRITE_F32) *(float4*)&outf[(size_t)t * DOUT + c0] = o;
        }
    }
}

// ---------------- cosine scores (bf16 embedding gathers) ----------------
// 16 lanes per pair (16 x ushort4 = 64 dims)
__global__ __launch_bounds__(256) void score_kernel(const u16* __restrict__ hu,
                                                    const u16* __restrict__ hi,
                                                    const int* __restrict__ pu,
                                                    const int* __restrict__ pi,
                                                    float* __restrict__ out, int P) {
    int g = threadIdx.x >> 4, l = threadIdx.x & 15;
    int p = blockIdx.x * 16 + g;
    if (p >= P) return;
    int u = pu[p], it = pi[p];
    ushort4 ua = *(const ushort4*)&hu[(size_t)u * 64 + (l << 2)];
    ushort4 ub = *(const ushort4*)&hi[(size_t)it * 64 + (l << 2)];
    float ax = bf2f(ua.x), ay = bf2f(ua.y), az = bf2f(ua.z), aw = bf2f(ua.w);
    float bx = bf2f(ub.x), by = bf2f(ub.y), bz = bf2f(ub.z), bw = bf2f(ub.w);
    float d  = ax * bx + ay * by + az * bz + aw * bw;
    float na = ax * ax + ay * ay + az * az + aw * aw;
    float nb = bx * bx + by * by + bz * bz + bw * bw;
    #pragma unroll
    for (int m = 1; m < 16; m <<= 1) {
        d  += __shfl_xor(d, m);
        na += __shfl_xor(na, m);
        nb += __shfl_xor(nb, m);
    }
    if (l == 0) out[p] = d / (fmaxf(sqrtf(na), 1e-12f) * fmaxf(sqrtf(nb), 1e-12f));
}

// ---------------- host ----------------

extern "C" void kernel_launch(void* const* d_in, const int* in_sizes, int n_in,
                              void* d_out, int out_size, void* d_ws, size_t ws_size,
                              hipStream_t stream) {
    const float* h_user = (const float*)d_in[0];
    const float* h_item = (const float*)d_in[1];
    const float* Wn01   = (const float*)d_in[2];
    const float* bn01   = (const float*)d_in[3];
    const float* Ws01   = (const float*)d_in[4];
    const float* bs01   = (const float*)d_in[5];
    const float* Wn2    = (const float*)d_in[6];
    const float* bn2    = (const float*)d_in[7];
    const float* Ws2    = (const float*)d_in[8];
    const float* bs2    = (const float*)d_in[9];
    const int* u2i_src  = (const int*)d_in[10];
    const int* u2i_dst  = (const int*)d_in[11];
    const int* i2u_src  = (const int*)d_in[12];
    const int* i2u_dst  = (const int*)d_in[13];
    const int* pos_u    = (const int*)d_in[14];
    const int* pos_i    = (const int*)d_in[15];
    const int* neg_u    = (const int*)d_in[16];
    const int* neg_i    = (const int*)d_in[17];

    float* out = (float*)d_out;
    float* out_hu = out;                       // [NU,64]
    float* out_hi = out + (size_t)NU * 64;     // [NI,64]
    float* out_pos = out + (size_t)NU * 64 + (size_t)NI * 64;
    float* out_neg = out_pos + NP;

    // workspace layout
    char* ws = (char*)d_ws;
    size_t off = 0;
    auto alloc = [&](size_t bytes) -> void* {
        void* p = ws + off;
        off = (off + bytes + 255) & ~(size_t)255;
        return p;
    };
    u16* hu0b = (u16*)alloc((size_t)NU * 128 * 2);   // bf16 copies of inputs
    u16* hi0b = (u16*)alloc((size_t)NI * 128 * 2);
    u16* hu_b = (u16*)alloc((size_t)NU * 128 * 2);   // layer intermediates (bf16)
    u16* hi_b = (u16*)alloc((size_t)NI * 128 * 2);
    u16* hu_a = (u16*)alloc((size_t)NU * 128 * 2);
    u16* hi_a = (u16*)alloc((size_t)NI * 128 * 2);
    u16* aggb = (u16*)alloc((size_t)NU * 128 * 2);   // agg output (bf16)
    u16* hu2b = (u16*)alloc((size_t)NU * 64 * 2);    // final embeddings (bf16, for scores)
    u16* hi2b = (u16*)alloc((size_t)NI * 64 * 2);
    int* csr_u2i = (int*)alloc((size_t)NE * 4);
    int* csr_i2u = (int*)alloc((size_t)NE * 4);
    int* rs_i   = (int*)alloc((size_t)(NI + 1) * 4);
    int* rs_u   = (int*)alloc((size_t)(NU + 1) * 4);
    int* deg    = (int*)alloc((size_t)NU * 4);
    int* cursor = (int*)alloc((size_t)NU * 4);
    int* bsum   = (int*)alloc(1024 * 4);
    (void)ws_size; (void)in_sizes; (void)n_in; (void)out_size;

    const int eblocks = (NE + 255) / 256;

    // ---- bf16 copies of input features ----
    cvt_kernel<<<(NU * 128 / 8 + 255) / 256, 256, 0, stream>>>(h_user, hu0b, NU * 128 / 8);
    cvt_kernel<<<(NI * 128 / 8 + 255) / 256, 256, 0, stream>>>(h_item, hi0b, NI * 128 / 8);

    // ---- CSR for u2i (dst = items) ----
    {
        hipMemsetAsync(deg, 0, (size_t)NI * 4, stream);
        hist_kernel<<<eblocks, 256, 0, stream>>>(u2i_dst, deg, NE);
        int nb = (NI + 1023) / 1024;
        scan_local_kernel<<<nb, 1024, 0, stream>>>(deg, rs_i, bsum, NI);
        scan_bsum_kernel<<<1, 1024, 0, stream>>>(bsum, nb);
        scan_finalize_kernel<<<nb, 1024, 0, stream>>>(rs_i, bsum, cursor, NI, NE);
        fill_kernel<<<eblocks, 256, 0, stream>>>(u2i_src, u2i_dst, cursor, csr_u2i, NE);
    }
    // ---- CSR for i2u (dst = users) ----
    {
        hipMemsetAsync(deg, 0, (size_t)NU * 4, stream);
        hist_kernel<<<eblocks, 256, 0, stream>>>(i2u_dst, deg, NE);
        int nb = (NU + 1023) / 1024;
        scan_local_kernel<<<nb, 1024, 0, stream>>>(deg, rs_u, bsum, NU);
        scan_bsum_kernel<<<1, 1024, 0, stream>>>(bsum, nb);
        scan_finalize_kernel<<<nb, 1024, 0, stream>>>(rs_u, bsum, cursor, NU, NE);
        fill_kernel<<<eblocks, 256, 0, stream>>>(i2u_src, i2u_dst, cursor, csr_i2u, NE);
    }

    const int gi = (NI + 3) / 4, gu = (NU + 3) / 4;          // agg grids
    const int ci = (NI + 31) / 32, cu = (NU + 31) / 32;      // conv grids

    // ---- layer 0 ----
    agg_kernel<<<gi, 256, 0, stream>>>(hu0b, rs_i, csr_u2i, aggb, NI);
    conv_kernel<128, false><<<ci, 256, 0, stream>>>(aggb, hi0b, Wn01 + 0, bn01 + 0,
                                                    Ws01 + 0, bs01 + 0, nullptr, hi_b, NI);
    agg_kernel<<<gu, 256, 0, stream>>>(hi0b, rs_u, csr_i2u, aggb, NU);
    conv_kernel<128, false><<<cu, 256, 0, stream>>>(aggb, hu0b, Wn01 + 16384, bn01 + 128,
                                                    Ws01 + 16384, bs01 + 128, nullptr, hu_b, NU);
    // ---- layer 1 ----
    agg_kernel<<<gi, 256, 0, stream>>>(hu_b, rs_i, csr_u2i, aggb, NI);
    conv_kernel<128, false><<<ci, 256, 0, stream>>>(aggb, hi_b, Wn01 + 32768, bn01 + 256,
                                                    Ws01 + 32768, bs01 + 256, nullptr, hi_a, NI);
    agg_kernel<<<gu, 256, 0, stream>>>(hi_b, rs_u, csr_i2u, aggb, NU);
    conv_kernel<128, false><<<cu, 256, 0, stream>>>(aggb, hu_b, Wn01 + 49152, bn01 + 384,
                                                    Ws01 + 49152, bs01 + 384, nullptr, hu_a, NU);
    // ---- layer 2 (writes d_out embeddings f32 + bf16 copy for scores) ----
    agg_kernel<<<gi, 256, 0, stream>>>(hu_a, rs_i, csr_u2i, aggb, NI);
    conv_kernel<64, true><<<ci, 256, 0, stream>>>(aggb, hi_a, Wn2 + 0, bn2 + 0,
                                                  Ws2 + 0, bs2 + 0, out_hi, hi2b, NI);
    agg_kernel<<<gu, 256, 0, stream>>>(hi_a, rs_u, csr_i2u, aggb, NU);
    conv_kernel<64, true><<<cu, 256, 0, stream>>>(aggb, hu_a, Wn2 + 8192, bn2 + 64,
                                                  Ws2 + 8192, bs2 + 64, out_hu, hu2b, NU);

    // ---- cosine scores ----
    const int pblocks = (NP + 15) / 16;
    score_kernel<<<pblocks, 256, 0, stream>>>(hu2b, hi2b, pos_u, pos_i, out_pos, NP);
    score_kernel<<<pblocks, 256, 0, stream>>>(hu2b, hi2b, neg_u, neg_i, out_neg, NP);
}

// Round 7
// 838.694 us; speedup vs baseline: 2.2658x; 1.4172x over previous
//
#include <hip/hip_runtime.h>
#include <hip/hip_bf16.h>

// Problem constants (from reference)
#define NU 100000
#define NI 50000
#define NE 1000000
#define NP 500000
// D_IN = D_HID = 128, D_OUT = 64

typedef unsigned short u16;
typedef unsigned int u32;
typedef __attribute__((ext_vector_type(8))) short short8;   // 8 bf16 (4 VGPRs)
typedef __attribute__((ext_vector_type(4))) float f32x4;

static __device__ __forceinline__ u16 f2bf(float f) {
    union { float f; u32 u; } x; x.f = f;
    u32 r = x.u + 0x7fff + ((x.u >> 16) & 1);   // round-to-nearest-even
    return (u16)(r >> 16);
}
static __device__ __forceinline__ float bf2f(u16 h) {
    union { u32 u; float f; } x; x.u = ((u32)h) << 16;
    return x.f;
}

// ---------------- f32 -> bf16 table conversion ----------------
__global__ __launch_bounds__(256) void cvt_kernel(const float* __restrict__ in,
                                                  u16* __restrict__ out, int n8) {
    int i = blockIdx.x * blockDim.x + threadIdx.x;
    if (i >= n8) return;
    float4 a = ((const float4*)in)[2 * i];
    float4 b = ((const float4*)in)[2 * i + 1];
    ushort4 lo = {f2bf(a.x), f2bf(a.y), f2bf(a.z), f2bf(a.w)};
    ushort4 hi = {f2bf(b.x), f2bf(b.y), f2bf(b.z), f2bf(b.w)};
    ((ushort4*)out)[2 * i]     = lo;
    ((ushort4*)out)[2 * i + 1] = hi;
}

// ---------------- weight transpose+cast: Wt[n][0:128]=Wn[:,n], Wt[n][128:256]=Ws[:,n] ----
__global__ void wtrans_kernel(const float* __restrict__ Wn, const float* __restrict__ Ws,
                              u16* __restrict__ Wt, int N) {
    int n = blockIdx.x;
    int k = threadIdx.x;   // blockDim = 128
    Wt[(size_t)n * 256 + k]       = f2bf(Wn[(size_t)k * N + n]);
    Wt[(size_t)n * 256 + 128 + k] = f2bf(Ws[(size_t)k * N + n]);
}

// ---------------- CSR build ----------------

__global__ void hist_kernel(const int* __restrict__ dst, int* __restrict__ deg, int E) {
    int e = blockIdx.x * blockDim.x + threadIdx.x;
    if (e < E) atomicAdd(&deg[dst[e]], 1);
}

__global__ void scan_local_kernel(const int* __restrict__ in, int* __restrict__ out,
                                  int* __restrict__ bsum, int n) {
    __shared__ int s[1024];
    int i = blockIdx.x * 1024 + threadIdx.x;
    int v = (i < n) ? in[i] : 0;
    s[threadIdx.x] = v;
    __syncthreads();
    for (int off = 1; off < 1024; off <<= 1) {
        int t = (threadIdx.x >= off) ? s[threadIdx.x - off] : 0;
        __syncthreads();
        s[threadIdx.x] += t;
        __syncthreads();
    }
    if (i < n) out[i] = s[threadIdx.x] - v;   // exclusive within block
    if (threadIdx.x == 1023) bsum[blockIdx.x] = s[1023];
}

__global__ void scan_bsum_kernel(int* bsum, int nb) {
    __shared__ int s[1024];
    int v = (threadIdx.x < nb) ? bsum[threadIdx.x] : 0;
    s[threadIdx.x] = v;
    __syncthreads();
    for (int off = 1; off < 1024; off <<= 1) {
        int t = (threadIdx.x >= off) ? s[threadIdx.x - off] : 0;
        __syncthreads();
        s[threadIdx.x] += t;
        __syncthreads();
    }
    if (threadIdx.x < nb) bsum[threadIdx.x] = s[threadIdx.x] - v;  // exclusive
}

__global__ void scan_finalize_kernel(int* __restrict__ rs, const int* __restrict__ bsum,
                                     int* __restrict__ cursor, int n, int E) {
    int i = blockIdx.x * 1024 + threadIdx.x;
    if (i < n) {
        int v = rs[i] + bsum[blockIdx.x];
        rs[i] = v;
        cursor[i] = v;
    }
    if (i == 0) rs[n] = E;
}

__global__ void fill_kernel(const int* __restrict__ src, const int* __restrict__ dst,
                            int* cursor, int* __restrict__ csr, int E) {
    int e = blockIdx.x * blockDim.x + threadIdx.x;
    if (e < E) {
        int p = atomicAdd(&cursor[dst[e]], 1);
        csr[p] = src[e];
    }
}

// ---------------- mean aggregation (CSR, atomic-free, bf16 tables) ----------------
// 4 dst nodes per 256-thread block; one wave per node; lane owns dims {2j,2j+1}.
// Unroll x4 for memory-level parallelism (gather-latency bound).
__global__ __launch_bounds__(256) void agg_kernel(const u16* __restrict__ hsrc,
                                                  const int* __restrict__ rs,
                                                  const int* __restrict__ csr,
                                                  u16* __restrict__ out, int T) {
    int t = blockIdx.x * 4 + (threadIdx.x >> 6);
    int j = (threadIdx.x & 63) << 1;
    if (t >= T) return;
    int e0 = rs[t], e1 = rs[t + 1];
    float a0 = 0.f, a1 = 0.f, b0 = 0.f, b1 = 0.f;
    int e = e0;
    for (; e + 3 < e1; e += 4) {
        int s0 = csr[e], s1 = csr[e + 1], s2 = csr[e + 2], s3 = csr[e + 3];
        ushort2 v0 = *(const ushort2*)&hsrc[(size_t)s0 * 128 + j];
        ushort2 v1 = *(const ushort2*)&hsrc[(size_t)s1 * 128 + j];
        ushort2 v2 = *(const ushort2*)&hsrc[(size_t)s2 * 128 + j];
        ushort2 v3 = *(const ushort2*)&hsrc[(size_t)s3 * 128 + j];
        a0 += bf2f(v0.x) + bf2f(v1.x);
        a1 += bf2f(v0.y) + bf2f(v1.y);
        b0 += bf2f(v2.x) + bf2f(v3.x);
        b1 += bf2f(v2.y) + bf2f(v3.y);
    }
    for (; e < e1; ++e) {
        int s0 = csr[e];
        ushort2 v0 = *(const ushort2*)&hsrc[(size_t)s0 * 128 + j];
        a0 += bf2f(v0.x);
        a1 += bf2f(v0.y);
    }
    a0 += b0; a1 += b1;
    float inv = (e1 > e0) ? 1.f / (float)(e1 - e0) : 0.f;
    ushort2 o = {f2bf(a0 * inv), f2bf(a1 * inv)};
    *(ushort2*)&out[(size_t)t * 128 + j] = o;
}

// ---------------- conv via MFMA: z = [hn|hd] @ Wt^T + bn + bs; relu; row L2-norm ----
// Block = 256 threads = 4 waves, 32 rows. Wave w owns cols [w*16*NF, ...).
// A-fragments straight from global (L1-resident 16KB tile); B from transposed
// bf16 weights Wt[n][k] (L2-resident). f32 MFMA accumulation.
// mfma_f32_16x16x32_bf16 layouts: A lane holds row=lane&15, k=(lane>>4)*8+j;
// B lane holds col=lane&15, same k; C/D col=lane&15, row=(lane>>4)*4+reg.
template <int DOUT, bool WRITE_F32>
__global__ __launch_bounds__(256) void conv_mfma_kernel(
    const u16* __restrict__ hn, const u16* __restrict__ hd,
    const u16* __restrict__ Wt, const float* __restrict__ bn,
    const float* __restrict__ bs, float* __restrict__ outf,
    u16* __restrict__ outb, int T)
{
    constexpr int NF = DOUT / 64;            // col fragments per wave (2 or 1)
    __shared__ float psum[4][32];
    const int tid  = threadIdx.x;
    const int wave = tid >> 6;
    const int lane = tid & 63;
    const int lr   = lane & 15;
    const int lg   = lane >> 4;              // 0..3
    const int lk   = lg << 3;                // k offset within 32-step
    const int t0   = blockIdx.x * 32;

    int rA0 = t0 + lr;       if (rA0 >= T) rA0 = T - 1;   // clamp; stores guarded
    int rA1 = t0 + 16 + lr;  if (rA1 >= T) rA1 = T - 1;

    const u16* wp[NF];
    float bias[NF];
    #pragma unroll
    for (int ni = 0; ni < NF; ++ni) {
        int col = wave * (16 * NF) + ni * 16 + lr;
        wp[ni] = Wt + (size_t)col * 256;
        bias[ni] = bn[col] + bs[col];
    }

    f32x4 acc[2][NF];
    #pragma unroll
    for (int mi = 0; mi < 2; ++mi)
        #pragma unroll
        for (int ni = 0; ni < NF; ++ni)
            acc[mi][ni] = (f32x4){0.f, 0.f, 0.f, 0.f};

    #pragma unroll
    for (int ks = 0; ks < 8; ++ks) {
        const int k = ks * 32 + lk;                    // [0,256)
        const u16* __restrict__ sA = (k < 128) ? hn : hd;
        const int kk = k & 127;
        short8 a0 = *(const short8*)&sA[(size_t)rA0 * 128 + kk];
        short8 a1 = *(const short8*)&sA[(size_t)rA1 * 128 + kk];
        #pragma unroll
        for (int ni = 0; ni < NF; ++ni) {
            short8 b = *(const short8*)&wp[ni][k];
            acc[0][ni] = __builtin_amdgcn_mfma_f32_16x16x32_bf16(a0, b, acc[0][ni], 0, 0, 0);
            acc[1][ni] = __builtin_amdgcn_mfma_f32_16x16x32_bf16(a1, b, acc[1][ni], 0, 0, 0);
        }
    }

    // bias + relu + per-row square-sum over this wave's cols
    float rsum[2][4];
    #pragma unroll
    for (int mi = 0; mi < 2; ++mi)
        #pragma unroll
        for (int j = 0; j < 4; ++j) {
            float s = 0.f;
            #pragma unroll
            for (int ni = 0; ni < NF; ++ni) {
                float z = fmaxf(acc[mi][ni][j] + bias[ni], 0.f);
                acc[mi][ni][j] = z;
                s = fmaf(z, z, s);
            }
            rsum[mi][j] = s;
        }
    // reduce over the 16 lanes holding the cols (masks 1..8 stay in-group)
    #pragma unroll
    for (int m = 1; m < 16; m <<= 1)
        #pragma unroll
        for (int mi = 0; mi < 2; ++mi)
            #pragma unroll
            for (int j = 0; j < 4; ++j)
                rsum[mi][j] += __shfl_xor(rsum[mi][j], m);
    if (lr == 0) {
        #pragma unroll
        for (int mi = 0; mi < 2; ++mi)
            #pragma unroll
            for (int j = 0; j < 4; ++j)
                psum[wave][mi * 16 + lg * 4 + j] = rsum[mi][j];
    }
    __syncthreads();

    #pragma unroll
    for (int mi = 0; mi < 2; ++mi) {
        const int row = mi * 16 + lg * 4;
        #pragma unroll
        for (int j = 0; j < 4; ++j) {
            float n2 = psum[0][row + j] + psum[1][row + j] +
                       psum[2][row + j] + psum[3][row + j];
            float inv = 1.f / fmaxf(sqrtf(n2), 1e-12f);
            int t = t0 + row + j;
            if (t < T) {
                #pragma unroll
                for (int ni = 0; ni < NF; ++ni) {
                    int col = wave * (16 * NF) + ni * 16 + lr;
                    float o = acc[mi][ni][j] * inv;
                    outb[(size_t)t * DOUT + col] = f2bf(o);
                    if (WRITE_F32) outf[(size_t)t * DOUT + col] = o;
                }
            }
        }
    }
}

// ---------------- cosine scores (bf16 embedding gathers) ----------------
// 16 lanes per pair (16 x ushort4 = 64 dims)
__global__ __launch_bounds__(256) void score_kernel(const u16* __restrict__ hu,
                                                    const u16* __restrict__ hi,
                                                    const int* __restrict__ pu,
                                                    const int* __restrict__ pi,
                                                    float* __restrict__ out, int P) {
    int g = threadIdx.x >> 4, l = threadIdx.x & 15;
    int p = blockIdx.x * 16 + g;
    if (p >= P) return;
    int u = pu[p], it = pi[p];
    ushort4 ua = *(const ushort4*)&hu[(size_t)u * 64 + (l << 2)];
    ushort4 ub = *(const ushort4*)&hi[(size_t)it * 64 + (l << 2)];
    float ax = bf2f(ua.x), ay = bf2f(ua.y), az = bf2f(ua.z), aw = bf2f(ua.w);
    float bx = bf2f(ub.x), by = bf2f(ub.y), bz = bf2f(ub.z), bw = bf2f(ub.w);
    float d  = ax * bx + ay * by + az * bz + aw * bw;
    float na = ax * ax + ay * ay + az * az + aw * aw;
    float nb = bx * bx + by * by + bz * bz + bw * bw;
    #pragma unroll
    for (int m = 1; m < 16; m <<= 1) {
        d  += __shfl_xor(d, m);
        na += __shfl_xor(na, m);
        nb += __shfl_xor(nb, m);
    }
    if (l == 0) out[p] = d / (fmaxf(sqrtf(na), 1e-12f) * fmaxf(sqrtf(nb), 1e-12f));
}

// ---------------- host ----------------

extern "C" void kernel_launch(void* const* d_in, const int* in_sizes, int n_in,
                              void* d_out, int out_size, void* d_ws, size_t ws_size,
                              hipStream_t stream) {
    const float* h_user = (const float*)d_in[0];
    const float* h_item = (const float*)d_in[1];
    const float* Wn01   = (const float*)d_in[2];
    const float* bn01   = (const float*)d_in[3];
    const float* Ws01   = (const float*)d_in[4];
    const float* bs01   = (const float*)d_in[5];
    const float* Wn2    = (const float*)d_in[6];
    const float* bn2    = (const float*)d_in[7];
    const float* Ws2    = (const float*)d_in[8];
    const float* bs2    = (const float*)d_in[9];
    const int* u2i_src  = (const int*)d_in[10];
    const int* u2i_dst  = (const int*)d_in[11];
    const int* i2u_src  = (const int*)d_in[12];
    const int* i2u_dst  = (const int*)d_in[13];
    const int* pos_u    = (const int*)d_in[14];
    const int* pos_i    = (const int*)d_in[15];
    const int* neg_u    = (const int*)d_in[16];
    const int* neg_i    = (const int*)d_in[17];

    float* out = (float*)d_out;
    float* out_hu = out;                       // [NU,64]
    float* out_hi = out + (size_t)NU * 64;     // [NI,64]
    float* out_pos = out + (size_t)NU * 64 + (size_t)NI * 64;
    float* out_neg = out_pos + NP;

    // workspace layout
    char* ws = (char*)d_ws;
    size_t off = 0;
    auto alloc = [&](size_t bytes) -> void* {
        void* p = ws + off;
        off = (off + bytes + 255) & ~(size_t)255;
        return p;
    };
    u16* hu0b = (u16*)alloc((size_t)NU * 128 * 2);   // bf16 copies of inputs
    u16* hi0b = (u16*)alloc((size_t)NI * 128 * 2);
    u16* hu_b = (u16*)alloc((size_t)NU * 128 * 2);   // layer intermediates (bf16)
    u16* hi_b = (u16*)alloc((size_t)NI * 128 * 2);
    u16* hu_a = (u16*)alloc((size_t)NU * 128 * 2);
    u16* hi_a = (u16*)alloc((size_t)NI * 128 * 2);
    u16* aggb = (u16*)alloc((size_t)NU * 128 * 2);   // agg output (bf16)
    u16* hu2b = (u16*)alloc((size_t)NU * 64 * 2);    // final embeddings (bf16, scores)
    u16* hi2b = (u16*)alloc((size_t)NI * 64 * 2);
    u16* wt_l0_i = (u16*)alloc((size_t)128 * 256 * 2);  // transposed bf16 weights
    u16* wt_l0_u = (u16*)alloc((size_t)128 * 256 * 2);
    u16* wt_l1_i = (u16*)alloc((size_t)128 * 256 * 2);
    u16* wt_l1_u = (u16*)alloc((size_t)128 * 256 * 2);
    u16* wt_l2_i = (u16*)alloc((size_t)64 * 256 * 2);
    u16* wt_l2_u = (u16*)alloc((size_t)64 * 256 * 2);
    int* csr_u2i = (int*)alloc((size_t)NE * 4);
    int* csr_i2u = (int*)alloc((size_t)NE * 4);
    int* rs_i   = (int*)alloc((size_t)(NI + 1) * 4);
    int* rs_u   = (int*)alloc((size_t)(NU + 1) * 4);
    int* deg    = (int*)alloc((size_t)NU * 4);
    int* cursor = (int*)alloc((size_t)NU * 4);
    int* bsum   = (int*)alloc(1024 * 4);
    (void)ws_size; (void)in_sizes; (void)n_in; (void)out_size;

    const int eblocks = (NE + 255) / 256;

    // ---- bf16 copies of input features + transposed bf16 weights ----
    cvt_kernel<<<(NU * 128 / 8 + 255) / 256, 256, 0, stream>>>(h_user, hu0b, NU * 128 / 8);
    cvt_kernel<<<(NI * 128 / 8 + 255) / 256, 256, 0, stream>>>(h_item, hi0b, NI * 128 / 8);
    wtrans_kernel<<<128, 128, 0, stream>>>(Wn01 + 0,     Ws01 + 0,     wt_l0_i, 128);
    wtrans_kernel<<<128, 128, 0, stream>>>(Wn01 + 16384, Ws01 + 16384, wt_l0_u, 128);
    wtrans_kernel<<<128, 128, 0, stream>>>(Wn01 + 32768, Ws01 + 32768, wt_l1_i, 128);
    wtrans_kernel<<<128, 128, 0, stream>>>(Wn01 + 49152, Ws01 + 49152, wt_l1_u, 128);
    wtrans_kernel<<<64, 128, 0, stream>>>(Wn2 + 0,    Ws2 + 0,    wt_l2_i, 64);
    wtrans_kernel<<<64, 128, 0, stream>>>(Wn2 + 8192, Ws2 + 8192, wt_l2_u, 64);

    // ---- CSR for u2i (dst = items) ----
    {
        hipMemsetAsync(deg, 0, (size_t)NI * 4, stream);
        hist_kernel<<<eblocks, 256, 0, stream>>>(u2i_dst, deg, NE);
        int nb = (NI + 1023) / 1024;
        scan_local_kernel<<<nb, 1024, 0, stream>>>(deg, rs_i, bsum, NI);
        scan_bsum_kernel<<<1, 1024, 0, stream>>>(bsum, nb);
        scan_finalize_kernel<<<nb, 1024, 0, stream>>>(rs_i, bsum, cursor, NI, NE);
        fill_kernel<<<eblocks, 256, 0, stream>>>(u2i_src, u2i_dst, cursor, csr_u2i, NE);
    }
    // ---- CSR for i2u (dst = users) ----
    {
        hipMemsetAsync(deg, 0, (size_t)NU * 4, stream);
        hist_kernel<<<eblocks, 256, 0, stream>>>(i2u_dst, deg, NE);
        int nb = (NU + 1023) / 1024;
        scan_local_kernel<<<nb, 1024, 0, stream>>>(deg, rs_u, bsum, NU);
        scan_bsum_kernel<<<1, 1024, 0, stream>>>(bsum, nb);
        scan_finalize_kernel<<<nb, 1024, 0, stream>>>(rs_u, bsum, cursor, NU, NE);
        fill_kernel<<<eblocks, 256, 0, stream>>>(i2u_src, i2u_dst, cursor, csr_i2u, NE);
    }

    const int gi = (NI + 3) / 4, gu = (NU + 3) / 4;          // agg grids
    const int ci = (NI + 31) / 32, cu = (NU + 31) / 32;      // conv grids

    // ---- layer 0 ----
    agg_kernel<<<gi, 256, 0, stream>>>(hu0b, rs_i, csr_u2i, aggb, NI);
    conv_mfma_kernel<128, false><<<ci, 256, 0, stream>>>(aggb, hi0b, wt_l0_i,
                                                         bn01 + 0, bs01 + 0,
                                                         nullptr, hi_b, NI);
    agg_kernel<<<gu, 256, 0, stream>>>(hi0b, rs_u, csr_i2u, aggb, NU);
    conv_mfma_kernel<128, false><<<cu, 256, 0, stream>>>(aggb, hu0b, wt_l0_u,
                                                         bn01 + 128, bs01 + 128,
                                                         nullptr, hu_b, NU);
    // ---- layer 1 ----
    agg_kernel<<<gi, 256, 0, stream>>>(hu_b, rs_i, csr_u2i, aggb, NI);
    conv_mfma_kernel<128, false><<<ci, 256, 0, stream>>>(aggb, hi_b, wt_l1_i,
                                                         bn01 + 256, bs01 + 256,
                                                         nullptr, hi_a, NI);
    agg_kernel<<<gu, 256, 0, stream>>>(hi_b, rs_u, csr_i2u, aggb, NU);
    conv_mfma_kernel<128, false><<<cu, 256, 0, stream>>>(aggb, hu_b, wt_l1_u,
                                                         bn01 + 384, bs01 + 384,
                                                         nullptr, hu_a, NU);
    // ---- layer 2 (writes d_out embeddings f32 + bf16 copy for scores) ----
    agg_kernel<<<gi, 256, 0, stream>>>(hu_a, rs_i, csr_u2i, aggb, NI);
    conv_mfma_kernel<64, true><<<ci, 256, 0, stream>>>(aggb, hi_a, wt_l2_i,
                                                       bn2 + 0, bs2 + 0,
                                                       out_hi, hi2b, NI);
    agg_kernel<<<gu, 256, 0, stream>>>(hi_a, rs_u, csr_i2u, aggb, NU);
    conv_mfma_kernel<64, true><<<cu, 256, 0, stream>>>(aggb, hu_a, wt_l2_u,
                                                       bn2 + 64, bs2 + 64,
                                                       out_hu, hu2b, NU);

    // ---- cosine scores ----
    const int pblocks = (NP + 15) / 16;
    score_kernel<<<pblocks, 256, 0, stream>>>(hu2b, hi2b, pos_u, pos_i, out_pos, NP);
    score_kernel<<<pblocks, 256, 0, stream>>>(hu2b, hi2b, neg_u, neg_i, out_neg, NP);
}

// Round 8
// 760.292 us; speedup vs baseline: 2.4995x; 1.1031x over previous
//
#include <hip/hip_runtime.h>
#include <hip/hip_bf16.h>

// Problem constants (from reference)
#define NU 100000
#define NI 50000
#define NE 1000000
#define NP 500000
// D_IN = D_HID = 128, D_OUT = 64

typedef unsigned short u16;
typedef unsigned int u32;
typedef __attribute__((ext_vector_type(8))) short short8;   // 8 bf16 (4 VGPRs)
typedef __attribute__((ext_vector_type(4))) float f32x4;

static __device__ __forceinline__ u16 f2bf(float f) {
    union { float f; u32 u; } x; x.f = f;
    u32 r = x.u + 0x7fff + ((x.u >> 16) & 1);   // round-to-nearest-even
    return (u16)(r >> 16);
}
static __device__ __forceinline__ float bf2f(u16 h) {
    union { u32 u; float f; } x; x.u = ((u32)h) << 16;
    return x.f;
}

// ---------------- f32 -> bf16 table conversion ----------------
__global__ __launch_bounds__(256) void cvt_kernel(const float* __restrict__ in,
                                                  u16* __restrict__ out, int n8) {
    int i = blockIdx.x * blockDim.x + threadIdx.x;
    if (i >= n8) return;
    float4 a = ((const float4*)in)[2 * i];
    float4 b = ((const float4*)in)[2 * i + 1];
    ushort4 lo = {f2bf(a.x), f2bf(a.y), f2bf(a.z), f2bf(a.w)};
    ushort4 hi = {f2bf(b.x), f2bf(b.y), f2bf(b.z), f2bf(b.w)};
    ((ushort4*)out)[2 * i]     = lo;
    ((ushort4*)out)[2 * i + 1] = hi;
}

// ---------------- weight transpose+cast: Wt[n][0:128]=Wn[:,n], Wt[n][128:256]=Ws[:,n] ----
__global__ void wtrans_kernel(const float* __restrict__ Wn, const float* __restrict__ Ws,
                              u16* __restrict__ Wt, int N) {
    int n = blockIdx.x;
    int k = threadIdx.x;   // blockDim = 128
    Wt[(size_t)n * 256 + k]       = f2bf(Wn[(size_t)k * N + n]);
    Wt[(size_t)n * 256 + 128 + k] = f2bf(Ws[(size_t)k * N + n]);
}

// ---------------- CSR build ----------------

__global__ void hist_kernel(const int* __restrict__ dst, int* __restrict__ deg, int E) {
    int e = blockIdx.x * blockDim.x + threadIdx.x;
    if (e < E) atomicAdd(&deg[dst[e]], 1);
}

__global__ void scan_local_kernel(const int* __restrict__ in, int* __restrict__ out,
                                  int* __restrict__ bsum, int n) {
    __shared__ int s[1024];
    int i = blockIdx.x * 1024 + threadIdx.x;
    int v = (i < n) ? in[i] : 0;
    s[threadIdx.x] = v;
    __syncthreads();
    for (int off = 1; off < 1024; off <<= 1) {
        int t = (threadIdx.x >= off) ? s[threadIdx.x - off] : 0;
        __syncthreads();
        s[threadIdx.x] += t;
        __syncthreads();
    }
    if (i < n) out[i] = s[threadIdx.x] - v;   // exclusive within block
    if (threadIdx.x == 1023) bsum[blockIdx.x] = s[1023];
}

__global__ void scan_bsum_kernel(int* bsum, int nb) {
    __shared__ int s[1024];
    int v = (threadIdx.x < nb) ? bsum[threadIdx.x] : 0;
    s[threadIdx.x] = v;
    __syncthreads();
    for (int off = 1; off < 1024; off <<= 1) {
        int t = (threadIdx.x >= off) ? s[threadIdx.x - off] : 0;
        __syncthreads();
        s[threadIdx.x] += t;
        __syncthreads();
    }
    if (threadIdx.x < nb) bsum[threadIdx.x] = s[threadIdx.x] - v;  // exclusive
}

__global__ void scan_finalize_kernel(int* __restrict__ rs, const int* __restrict__ bsum,
                                     int* __restrict__ cursor, int n, int E) {
    int i = blockIdx.x * 1024 + threadIdx.x;
    if (i < n) {
        int v = rs[i] + bsum[blockIdx.x];
        rs[i] = v;
        cursor[i] = v;
    }
    if (i == 0) rs[n] = E;
}

// dst-range partitioned fill: blockIdx.y = pass, each pass fills csr positions
// for dst in [pass*chunk, (pass+1)*chunk) only. x-major dispatch order keeps
// each ~512KB csr window L2-resident so scattered 4B stores coalesce into
// full lines before eviction (round-7 profile: unpartitioned fill wrote 67MB
// HBM for a 4MB buffer).
__global__ void fill_kernel(const int* __restrict__ src, const int* __restrict__ dst,
                            int* cursor, int* __restrict__ csr, int E, int n) {
    int e = blockIdx.x * blockDim.x + threadIdx.x;
    if (e >= E) return;
    int d = dst[e];
    int chunk = (n + 7) >> 3;
    int lo = blockIdx.y * chunk;
    if (d >= lo && d < lo + chunk) {
        int p = atomicAdd(&cursor[d], 1);
        csr[p] = src[e];
    }
}

// ---------------- mean aggregation (CSR, atomic-free, bf16 tables) ----------------
// 4 dst nodes per 256-thread block; one wave per node.
// 16 lanes per edge-row (ushort8 = 16B each), 4 edge-rows per wave per batch,
// unrolled x2 => 8 rows in flight; cross-sub shfl_xor(16/32) reduce at end.
__global__ __launch_bounds__(256) void agg_kernel(const u16* __restrict__ hsrc,
                                                  const int* __restrict__ rs,
                                                  const int* __restrict__ csr,
                                                  u16* __restrict__ out, int T) {
    int t = blockIdx.x * 4 + (threadIdx.x >> 6);
    if (t >= T) return;
    const int lane = threadIdx.x & 63;
    const int lr   = lane & 15;        // dims lr*8 .. lr*8+7
    const int sub  = lane >> 4;        // edge slot 0..3
    int e0 = rs[t], e1 = rs[t + 1];
    float acc[8] = {};
    int e = e0 + sub;
    for (; e + 4 < e1; e += 8) {
        int s0 = csr[e], s1 = csr[e + 4];
        short8 v0 = *(const short8*)&hsrc[(size_t)s0 * 128 + (lr << 3)];
        short8 v1 = *(const short8*)&hsrc[(size_t)s1 * 128 + (lr << 3)];
        #pragma unroll
        for (int q = 0; q < 8; ++q)
            acc[q] += bf2f((u16)v0[q]) + bf2f((u16)v1[q]);
    }
    if (e < e1) {
        int s0 = csr[e];
        short8 v0 = *(const short8*)&hsrc[(size_t)s0 * 128 + (lr << 3)];
        #pragma unroll
        for (int q = 0; q < 8; ++q) acc[q] += bf2f((u16)v0[q]);
    }
    // reduce across the 4 edge slots (lanes differing in bits 4,5)
    #pragma unroll
    for (int q = 0; q < 8; ++q) {
        acc[q] += __shfl_xor(acc[q], 16);
        acc[q] += __shfl_xor(acc[q], 32);
    }
    if (sub == 0) {
        float inv = (e1 > e0) ? 1.f / (float)(e1 - e0) : 0.f;
        short8 o;
        #pragma unroll
        for (int q = 0; q < 8; ++q) o[q] = (short)f2bf(acc[q] * inv);
        *(short8*)&out[(size_t)t * 128 + (lr << 3)] = o;
    }
}

// ---------------- conv via MFMA: z = [hn|hd] @ Wt^T + bn + bs; relu; row L2-norm ----
// Block = 256 threads = 4 waves, 32 rows. Wave w owns cols [w*16*NF, ...).
// A-fragments straight from global (L1-resident 16KB tile); B from transposed
// bf16 weights Wt[n][k] (L2-resident). f32 MFMA accumulation.
template <int DOUT, bool WRITE_F32>
__global__ __launch_bounds__(256) void conv_mfma_kernel(
    const u16* __restrict__ hn, const u16* __restrict__ hd,
    const u16* __restrict__ Wt, const float* __restrict__ bn,
    const float* __restrict__ bs, float* __restrict__ outf,
    u16* __restrict__ outb, int T)
{
    constexpr int NF = DOUT / 64;            // col fragments per wave (2 or 1)
    __shared__ float psum[4][32];
    const int tid  = threadIdx.x;
    const int wave = tid >> 6;
    const int lane = tid & 63;
    const int lr   = lane & 15;
    const int lg   = lane >> 4;              // 0..3
    const int lk   = lg << 3;                // k offset within 32-step
    const int t0   = blockIdx.x * 32;

    int rA0 = t0 + lr;       if (rA0 >= T) rA0 = T - 1;   // clamp; stores guarded
    int rA1 = t0 + 16 + lr;  if (rA1 >= T) rA1 = T - 1;

    const u16* wp[NF];
    float bias[NF];
    #pragma unroll
    for (int ni = 0; ni < NF; ++ni) {
        int col = wave * (16 * NF) + ni * 16 + lr;
        wp[ni] = Wt + (size_t)col * 256;
        bias[ni] = bn[col] + bs[col];
    }

    f32x4 acc[2][NF];
    #pragma unroll
    for (int mi = 0; mi < 2; ++mi)
        #pragma unroll
        for (int ni = 0; ni < NF; ++ni)
            acc[mi][ni] = (f32x4){0.f, 0.f, 0.f, 0.f};

    #pragma unroll
    for (int ks = 0; ks < 8; ++ks) {
        const int k = ks * 32 + lk;                    // [0,256)
        const u16* __restrict__ sA = (k < 128) ? hn : hd;
        const int kk = k & 127;
        short8 a0 = *(const short8*)&sA[(size_t)rA0 * 128 + kk];
        short8 a1 = *(const short8*)&sA[(size_t)rA1 * 128 + kk];
        #pragma unroll
        for (int ni = 0; ni < NF; ++ni) {
            short8 b = *(const short8*)&wp[ni][k];
            acc[0][ni] = __builtin_amdgcn_mfma_f32_16x16x32_bf16(a0, b, acc[0][ni], 0, 0, 0);
            acc[1][ni] = __builtin_amdgcn_mfma_f32_16x16x32_bf16(a1, b, acc[1][ni], 0, 0, 0);
        }
    }

    // bias + relu + per-row square-sum over this wave's cols
    float rsum[2][4];
    #pragma unroll
    for (int mi = 0; mi < 2; ++mi)
        #pragma unroll
        for (int j = 0; j < 4; ++j) {
            float s = 0.f;
            #pragma unroll
            for (int ni = 0; ni < NF; ++ni) {
                float z = fmaxf(acc[mi][ni][j] + bias[ni], 0.f);
                acc[mi][ni][j] = z;
                s = fmaf(z, z, s);
            }
            rsum[mi][j] = s;
        }
    // reduce over the 16 lanes holding the cols
    #pragma unroll
    for (int m = 1; m < 16; m <<= 1)
        #pragma unroll
        for (int mi = 0; mi < 2; ++mi)
            #pragma unroll
            for (int j = 0; j < 4; ++j)
                rsum[mi][j] += __shfl_xor(rsum[mi][j], m);
    if (lr == 0) {
        #pragma unroll
        for (int mi = 0; mi < 2; ++mi)
            #pragma unroll
            for (int j = 0; j < 4; ++j)
                psum[wave][mi * 16 + lg * 4 + j] = rsum[mi][j];
    }
    __syncthreads();

    #pragma unroll
    for (int mi = 0; mi < 2; ++mi) {
        const int row = mi * 16 + lg * 4;
        #pragma unroll
        for (int j = 0; j < 4; ++j) {
            float n2 = psum[0][row + j] + psum[1][row + j] +
                       psum[2][row + j] + psum[3][row + j];
            float inv = 1.f / fmaxf(sqrtf(n2), 1e-12f);
            int t = t0 + row + j;
            if (t < T) {
                #pragma unroll
                for (int ni = 0; ni < NF; ++ni) {
                    int col = wave * (16 * NF) + ni * 16 + lr;
                    float o = acc[mi][ni][j] * inv;
                    outb[(size_t)t * DOUT + col] = f2bf(o);
                    if (WRITE_F32) outf[(size_t)t * DOUT + col] = o;
                }
            }
        }
    }
}

// ---------------- cosine scores (bf16 embedding gathers) ----------------
// 8 lanes per pair (8 x ushort8 = 64 dims, 16B/lane)
__global__ __launch_bounds__(256) void score_kernel(const u16* __restrict__ hu,
                                                    const u16* __restrict__ hi,
                                                    const int* __restrict__ pu,
                                                    const int* __restrict__ pi,
                                                    float* __restrict__ out, int P) {
    int g = threadIdx.x >> 3, l = threadIdx.x & 7;
    int p = blockIdx.x * 32 + g;
    if (p >= P) return;
    int u = pu[p], it = pi[p];
    short8 a = *(const short8*)&hu[(size_t)u * 64 + (l << 3)];
    short8 b = *(const short8*)&hi[(size_t)it * 64 + (l << 3)];
    float d = 0.f, na = 0.f, nb = 0.f;
    #pragma unroll
    for (int q = 0; q < 8; ++q) {
        float x = bf2f((u16)a[q]), y = bf2f((u16)b[q]);
        d  = fmaf(x, y, d);
        na = fmaf(x, x, na);
        nb = fmaf(y, y, nb);
    }
    #pragma unroll
    for (int m = 1; m < 8; m <<= 1) {
        d  += __shfl_xor(d, m);
        na += __shfl_xor(na, m);
        nb += __shfl_xor(nb, m);
    }
    if (l == 0) out[p] = d / (fmaxf(sqrtf(na), 1e-12f) * fmaxf(sqrtf(nb), 1e-12f));
}

// ---------------- host ----------------

extern "C" void kernel_launch(void* const* d_in, const int* in_sizes, int n_in,
                              void* d_out, int out_size, void* d_ws, size_t ws_size,
                              hipStream_t stream) {
    const float* h_user = (const float*)d_in[0];
    const float* h_item = (const float*)d_in[1];
    const float* Wn01   = (const float*)d_in[2];
    const float* bn01   = (const float*)d_in[3];
    const float* Ws01   = (const float*)d_in[4];
    const float* bs01   = (const float*)d_in[5];
    const float* Wn2    = (const float*)d_in[6];
    const float* bn2    = (const float*)d_in[7];
    const float* Ws2    = (const float*)d_in[8];
    const float* bs2    = (const float*)d_in[9];
    const int* u2i_src  = (const int*)d_in[10];
    const int* u2i_dst  = (const int*)d_in[11];
    const int* i2u_src  = (const int*)d_in[12];
    const int* i2u_dst  = (const int*)d_in[13];
    const int* pos_u    = (const int*)d_in[14];
    const int* pos_i    = (const int*)d_in[15];
    const int* neg_u    = (const int*)d_in[16];
    const int* neg_i    = (const int*)d_in[17];

    float* out = (float*)d_out;
    float* out_hu = out;                       // [NU,64]
    float* out_hi = out + (size_t)NU * 64;     // [NI,64]
    float* out_pos = out + (size_t)NU * 64 + (size_t)NI * 64;
    float* out_neg = out_pos + NP;

    // workspace layout
    char* ws = (char*)d_ws;
    size_t off = 0;
    auto alloc = [&](size_t bytes) -> void* {
        void* p = ws + off;
        off = (off + bytes + 255) & ~(size_t)255;
        return p;
    };
    u16* hu0b = (u16*)alloc((size_t)NU * 128 * 2);   // bf16 copies of inputs
    u16* hi0b = (u16*)alloc((size_t)NI * 128 * 2);
    u16* hu_b = (u16*)alloc((size_t)NU * 128 * 2);   // layer intermediates (bf16)
    u16* hi_b = (u16*)alloc((size_t)NI * 128 * 2);
    u16* hu_a = (u16*)alloc((size_t)NU * 128 * 2);
    u16* hi_a = (u16*)alloc((size_t)NI * 128 * 2);
    u16* aggb = (u16*)alloc((size_t)NU * 128 * 2);   // agg output (bf16)
    u16* hu2b = (u16*)alloc((size_t)NU * 64 * 2);    // final embeddings (bf16, scores)
    u16* hi2b = (u16*)alloc((size_t)NI * 64 * 2);
    u16* wt_l0_i = (u16*)alloc((size_t)128 * 256 * 2);  // transposed bf16 weights
    u16* wt_l0_u = (u16*)alloc((size_t)128 * 256 * 2);
    u16* wt_l1_i = (u16*)alloc((size_t)128 * 256 * 2);
    u16* wt_l1_u = (u16*)alloc((size_t)128 * 256 * 2);
    u16* wt_l2_i = (u16*)alloc((size_t)64 * 256 * 2);
    u16* wt_l2_u = (u16*)alloc((size_t)64 * 256 * 2);
    int* csr_u2i = (int*)alloc((size_t)NE * 4);
    int* csr_i2u = (int*)alloc((size_t)NE * 4);
    int* rs_i   = (int*)alloc((size_t)(NI + 1) * 4);
    int* rs_u   = (int*)alloc((size_t)(NU + 1) * 4);
    int* deg    = (int*)alloc((size_t)NU * 4);
    int* cursor = (int*)alloc((size_t)NU * 4);
    int* bsum   = (int*)alloc(1024 * 4);
    (void)ws_size; (void)in_sizes; (void)n_in; (void)out_size;

    const int eblocks = (NE + 255) / 256;

    // ---- bf16 copies of input features + transposed bf16 weights ----
    cvt_kernel<<<(NU * 128 / 8 + 255) / 256, 256, 0, stream>>>(h_user, hu0b, NU * 128 / 8);
    cvt_kernel<<<(NI * 128 / 8 + 255) / 256, 256, 0, stream>>>(h_item, hi0b, NI * 128 / 8);
    wtrans_kernel<<<128, 128, 0, stream>>>(Wn01 + 0,     Ws01 + 0,     wt_l0_i, 128);
    wtrans_kernel<<<128, 128, 0, stream>>>(Wn01 + 16384, Ws01 + 16384, wt_l0_u, 128);
    wtrans_kernel<<<128, 128, 0, stream>>>(Wn01 + 32768, Ws01 + 32768, wt_l1_i, 128);
    wtrans_kernel<<<128, 128, 0, stream>>>(Wn01 + 49152, Ws01 + 49152, wt_l1_u, 128);
    wtrans_kernel<<<64, 128, 0, stream>>>(Wn2 + 0,    Ws2 + 0,    wt_l2_i, 64);
    wtrans_kernel<<<64, 128, 0, stream>>>(Wn2 + 8192, Ws2 + 8192, wt_l2_u, 64);

    // ---- CSR for u2i (dst = items) ----
    {
        hipMemsetAsync(deg, 0, (size_t)NI * 4, stream);
        hist_kernel<<<eblocks, 256, 0, stream>>>(u2i_dst, deg, NE);
        int nb = (NI + 1023) / 1024;
        scan_local_kernel<<<nb, 1024, 0, stream>>>(deg, rs_i, bsum, NI);
        scan_bsum_kernel<<<1, 1024, 0, stream>>>(bsum, nb);
        scan_finalize_kernel<<<nb, 1024, 0, stream>>>(rs_i, bsum, cursor, NI, NE);
        fill_kernel<<<dim3(eblocks, 8), 256, 0, stream>>>(u2i_src, u2i_dst, cursor,
                                                          csr_u2i, NE, NI);
    }
    // ---- CSR for i2u (dst = users) ----
    {
        hipMemsetAsync(deg, 0, (size_t)NU * 4, stream);
        hist_kernel<<<eblocks, 256, 0, stream>>>(i2u_dst, deg, NE);
        int nb = (NU + 1023) / 1024;
        scan_local_kernel<<<nb, 1024, 0, stream>>>(deg, rs_u, bsum, NU);
        scan_bsum_kernel<<<1, 1024, 0, stream>>>(bsum, nb);
        scan_finalize_kernel<<<nb, 1024, 0, stream>>>(rs_u, bsum, cursor, NU, NE);
        fill_kernel<<<dim3(eblocks, 8), 256, 0, stream>>>(i2u_src, i2u_dst, cursor,
                                                          csr_i2u, NE, NU);
    }

    const int gi = (NI + 3) / 4, gu = (NU + 3) / 4;          // agg grids
    const int ci = (NI + 31) / 32, cu = (NU + 31) / 32;      // conv grids

    // ---- layer 0 ----
    agg_kernel<<<gi, 256, 0, stream>>>(hu0b, rs_i, csr_u2i, aggb, NI);
    conv_mfma_kernel<128, false><<<ci, 256, 0, stream>>>(aggb, hi0b, wt_l0_i,
                                                         bn01 + 0, bs01 + 0,
                                                         nullptr, hi_b, NI);
    agg_kernel<<<gu, 256, 0, stream>>>(hi0b, rs_u, csr_i2u, aggb, NU);
    conv_mfma_kernel<128, false><<<cu, 256, 0, stream>>>(aggb, hu0b, wt_l0_u,
                                                         bn01 + 128, bs01 + 128,
                                                         nullptr, hu_b, NU);
    // ---- layer 1 ----
    agg_kernel<<<gi, 256, 0, stream>>>(hu_b, rs_i, csr_u2i, aggb, NI);
    conv_mfma_kernel<128, false><<<ci, 256, 0, stream>>>(aggb, hi_b, wt_l1_i,
                                                         bn01 + 256, bs01 + 256,
                                                         nullptr, hi_a, NI);
    agg_kernel<<<gu, 256, 0, stream>>>(hi_b, rs_u, csr_i2u, aggb, NU);
    conv_mfma_kernel<128, false><<<cu, 256, 0, stream>>>(aggb, hu_b, wt_l1_u,
                                                         bn01 + 384, bs01 + 384,
                                                         nullptr, hu_a, NU);
    // ---- layer 2 (writes d_out embeddings f32 + bf16 copy for scores) ----
    agg_kernel<<<gi, 256, 0, stream>>>(hu_a, rs_i, csr_u2i, aggb, NI);
    conv_mfma_kernel<64, true><<<ci, 256, 0, stream>>>(aggb, hi_a, wt_l2_i,
                                                       bn2 + 0, bs2 + 0,
                                                       out_hi, hi2b, NI);
    agg_kernel<<<gu, 256, 0, stream>>>(hi_a, rs_u, csr_i2u, aggb, NU);
    conv_mfma_kernel<64, true><<<cu, 256, 0, stream>>>(aggb, hu_a, wt_l2_u,
                                                       bn2 + 64, bs2 + 64,
                                                       out_hu, hu2b, NU);

    // ---- cosine scores ----
    const int pblocks = (NP + 31) / 32;
    score_kernel<<<pblocks, 256, 0, stream>>>(hu2b, hi2b, pos_u, pos_i, out_pos, NP);
    score_kernel<<<pblocks, 256, 0, stream>>>(hu2b, hi2b, neg_u, neg_i, out_neg, NP);
}

// Round 9
// 632.451 us; speedup vs baseline: 3.0047x; 1.2021x over previous
//
#include <hip/hip_runtime.h>
#include <hip/hip_bf16.h>

// Problem constants (from reference)
#define NU 100000
#define NI 50000
#define NE 1000000
#define NP 500000
// D_IN = D_HID = 128, D_OUT = 64

typedef unsigned short u16;
typedef unsigned int u32;
typedef __attribute__((ext_vector_type(8))) short short8;   // 8 bf16 (4 VGPRs)
typedef __attribute__((ext_vector_type(4))) float f32x4;

static __device__ __forceinline__ u16 f2bf(float f) {
    union { float f; u32 u; } x; x.f = f;
    u32 r = x.u + 0x7fff + ((x.u >> 16) & 1);   // round-to-nearest-even
    return (u16)(r >> 16);
}
static __device__ __forceinline__ float bf2f(u16 h) {
    union { u32 u; float f; } x; x.u = ((u32)h) << 16;
    return x.f;
}

// ---------------- f32 -> bf16 table conversion ----------------
__global__ __launch_bounds__(256) void cvt_kernel(const float* __restrict__ in,
                                                  u16* __restrict__ out, int n8) {
    int i = blockIdx.x * blockDim.x + threadIdx.x;
    if (i >= n8) return;
    float4 a = ((const float4*)in)[2 * i];
    float4 b = ((const float4*)in)[2 * i + 1];
    ushort4 lo = {f2bf(a.x), f2bf(a.y), f2bf(a.z), f2bf(a.w)};
    ushort4 hi = {f2bf(b.x), f2bf(b.y), f2bf(b.z), f2bf(b.w)};
    ((ushort4*)out)[2 * i]     = lo;
    ((ushort4*)out)[2 * i + 1] = hi;
}

// ---------------- weight transpose+cast: Wt[n][0:128]=Wn[:,n], Wt[n][128:256]=Ws[:,n] ----
__global__ void wtrans_kernel(const float* __restrict__ Wn, const float* __restrict__ Ws,
                              u16* __restrict__ Wt, int N) {
    int n = blockIdx.x;
    int k = threadIdx.x;   // blockDim = 128
    Wt[(size_t)n * 256 + k]       = f2bf(Wn[(size_t)k * N + n]);
    Wt[(size_t)n * 256 + 128 + k] = f2bf(Ws[(size_t)k * N + n]);
}

// ---------------- CSR build ----------------

__global__ void hist_kernel(const int* __restrict__ dst, int* __restrict__ deg, int E) {
    int e = blockIdx.x * blockDim.x + threadIdx.x;
    if (e < E) atomicAdd(&deg[dst[e]], 1);
}

__global__ void scan_local_kernel(const int* __restrict__ in, int* __restrict__ out,
                                  int* __restrict__ bsum, int n) {
    __shared__ int s[1024];
    int i = blockIdx.x * 1024 + threadIdx.x;
    int v = (i < n) ? in[i] : 0;
    s[threadIdx.x] = v;
    __syncthreads();
    for (int off = 1; off < 1024; off <<= 1) {
        int t = (threadIdx.x >= off) ? s[threadIdx.x - off] : 0;
        __syncthreads();
        s[threadIdx.x] += t;
        __syncthreads();
    }
    if (i < n) out[i] = s[threadIdx.x] - v;   // exclusive within block
    if (threadIdx.x == 1023) bsum[blockIdx.x] = s[1023];
}

__global__ void scan_bsum_kernel(int* bsum, int nb) {
    __shared__ int s[1024];
    int v = (threadIdx.x < nb) ? bsum[threadIdx.x] : 0;
    s[threadIdx.x] = v;
    __syncthreads();
    for (int off = 1; off < 1024; off <<= 1) {
        int t = (threadIdx.x >= off) ? s[threadIdx.x - off] : 0;
        __syncthreads();
        s[threadIdx.x] += t;
        __syncthreads();
    }
    if (threadIdx.x < nb) bsum[threadIdx.x] = s[threadIdx.x] - v;  // exclusive
}

__global__ void scan_finalize_kernel(int* __restrict__ rs, const int* __restrict__ bsum,
                                     int* __restrict__ cursor, int n, int E) {
    int i = blockIdx.x * 1024 + threadIdx.x;
    if (i < n) {
        int v = rs[i] + bsum[blockIdx.x];
        rs[i] = v;
        cursor[i] = v;
    }
    if (i == 0) rs[n] = E;
}

// XCD-aligned dst-partitioned fill. Dispatch round-robins blocks over the 8
// XCDs, so window = blockIdx.x & 7 pins each csr/cursor window to ONE XCD's
// L2: scattered 4B stores accumulate into full lines in a single L2 (round-8
// profile: dispatch-contiguous windows still wrote 52MB HBM for a 4MB buffer
// because every window was dirtied in all 8 non-coherent L2s).
__global__ void fill_kernel(const int* __restrict__ src, const int* __restrict__ dst,
                            int* cursor, int* __restrict__ csr, int E, int n) {
    int window = blockIdx.x & 7;
    int e = (blockIdx.x >> 3) * blockDim.x + threadIdx.x;
    if (e >= E) return;
    int d = dst[e];
    int chunk = (n + 7) >> 3;
    int lo = window * chunk;
    if (d >= lo && d < lo + chunk) {
        int p = atomicAdd(&cursor[d], 1);
        csr[p] = src[e];
    }
}

// ---------------- mean aggregation (CSR, atomic-free, bf16 tables) ----------------
// 4 dst nodes per 256-thread block; one wave per node.
// 16 lanes per edge-row (ushort8 = 16B each), 4 edge-rows per wave per batch,
// unrolled x2 => 8 rows in flight; cross-sub shfl_xor(16/32) reduce at end.
__global__ __launch_bounds__(256) void agg_kernel(const u16* __restrict__ hsrc,
                                                  const int* __restrict__ rs,
                                                  const int* __restrict__ csr,
                                                  u16* __restrict__ out, int T) {
    int t = blockIdx.x * 4 + (threadIdx.x >> 6);
    if (t >= T) return;
    const int lane = threadIdx.x & 63;
    const int lr   = lane & 15;        // dims lr*8 .. lr*8+7
    const int sub  = lane >> 4;        // edge slot 0..3
    int e0 = rs[t], e1 = rs[t + 1];
    float acc[8] = {};
    int e = e0 + sub;
    for (; e + 4 < e1; e += 8) {
        int s0 = csr[e], s1 = csr[e + 4];
        short8 v0 = *(const short8*)&hsrc[(size_t)s0 * 128 + (lr << 3)];
        short8 v1 = *(const short8*)&hsrc[(size_t)s1 * 128 + (lr << 3)];
        #pragma unroll
        for (int q = 0; q < 8; ++q)
            acc[q] += bf2f((u16)v0[q]) + bf2f((u16)v1[q]);
    }
    if (e < e1) {
        int s0 = csr[e];
        short8 v0 = *(const short8*)&hsrc[(size_t)s0 * 128 + (lr << 3)];
        #pragma unroll
        for (int q = 0; q < 8; ++q) acc[q] += bf2f((u16)v0[q]);
    }
    // reduce across the 4 edge slots (lanes differing in bits 4,5)
    #pragma unroll
    for (int q = 0; q < 8; ++q) {
        acc[q] += __shfl_xor(acc[q], 16);
        acc[q] += __shfl_xor(acc[q], 32);
    }
    if (sub == 0) {
        float inv = (e1 > e0) ? 1.f / (float)(e1 - e0) : 0.f;
        short8 o;
        #pragma unroll
        for (int q = 0; q < 8; ++q) o[q] = (short)f2bf(acc[q] * inv);
        *(short8*)&out[(size_t)t * 128 + (lr << 3)] = o;
    }
}

// ---------------- conv via MFMA: z = [hn|hd] @ Wt^T + bn + bs; relu; row L2-norm ----
// Block = 256 threads = 4 waves, 64-row tile. A staged ONCE in LDS (coalesced
// 16B loads; 264-u16 row stride -> 2-way-free banks on ds_read_b128 frags).
// Wave w owns cols [w*16*NF, ...), 4 row-frags each. Epilogue transposes the
// normalized output through LDS so global stores are 16B/lane coalesced.
template <int DOUT, bool WRITE_F32>
__global__ __launch_bounds__(256) void conv_mfma_kernel(
    const u16* __restrict__ hn, const u16* __restrict__ hd,
    const u16* __restrict__ Wt, const float* __restrict__ bn,
    const float* __restrict__ bs, float* __restrict__ outf,
    u16* __restrict__ outb, int T)
{
    constexpr int NF   = DOUT / 64;               // col fragments per wave (2 or 1)
    constexpr int FSTR = (DOUT == 128) ? 132 : 68; // f32 out stride (16B-aligned rows)
    __shared__ u16 smA[64 * 264];                  // 33792 B, reused as f32 out
    __shared__ float psum[4][64];
    __shared__ float sinv[64];
    float* smF = (float*)smA;

    const int tid  = threadIdx.x;
    const int wave = tid >> 6;
    const int lane = tid & 63;
    const int lr   = lane & 15;
    const int lg   = lane >> 4;                    // 0..3
    const int t0   = blockIdx.x * 64;

    // ---- stage A = [hn | hd]: 64 rows x 256 u16, 16B per thread-chunk ----
    #pragma unroll
    for (int i = 0; i < 8; ++i) {
        int lin = i * 256 + tid;                   // 0..2047
        int row = lin >> 5;
        int q   = lin & 31;                        // 16B chunk within row
        int t   = t0 + row; if (t >= T) t = T - 1; // clamp; stores guarded
        const u16* srcp = (q < 16) ? &hn[(size_t)t * 128 + (q << 3)]
                                   : &hd[(size_t)t * 128 + ((q - 16) << 3)];
        *(short8*)&smA[row * 264 + (q << 3)] = *(const short8*)srcp;
    }
    __syncthreads();

    const u16* wp[NF];
    float bias[NF];
    #pragma unroll
    for (int ni = 0; ni < NF; ++ni) {
        int col = wave * (16 * NF) + ni * 16 + lr;
        wp[ni] = Wt + (size_t)col * 256;
        bias[ni] = bn[col] + bs[col];
    }

    f32x4 acc[4][NF];
    #pragma unroll
    for (int mi = 0; mi < 4; ++mi)
        #pragma unroll
        for (int ni = 0; ni < NF; ++ni)
            acc[mi][ni] = (f32x4){0.f, 0.f, 0.f, 0.f};

    #pragma unroll
    for (int ks = 0; ks < 8; ++ks) {
        const int kb = ks * 32 + (lg << 3);
        short8 b[NF];
        #pragma unroll
        for (int ni = 0; ni < NF; ++ni) b[ni] = *(const short8*)&wp[ni][kb];
        #pragma unroll
        for (int mi = 0; mi < 4; ++mi) {
            short8 a = *(const short8*)&smA[(mi * 16 + lr) * 264 + kb];
            #pragma unroll
            for (int ni = 0; ni < NF; ++ni)
                acc[mi][ni] = __builtin_amdgcn_mfma_f32_16x16x32_bf16(a, b[ni], acc[mi][ni], 0, 0, 0);
        }
    }
    __syncthreads();   // all waves done reading smA before overwrite as f32

    // bias + relu; z -> LDS (transpose buffer); per-row partial square-sums
    float rsum[4][4];
    #pragma unroll
    for (int mi = 0; mi < 4; ++mi) {
        #pragma unroll
        for (int j = 0; j < 4; ++j) {
            int rowg = mi * 16 + lg * 4 + j;
            float s = 0.f;
            #pragma unroll
            for (int ni = 0; ni < NF; ++ni) {
                float z = fmaxf(acc[mi][ni][j] + bias[ni], 0.f);
                int colg = wave * (16 * NF) + ni * 16 + lr;
                smF[rowg * FSTR + colg] = z;
                s = fmaf(z, z, s);
            }
            rsum[mi][j] = s;
        }
    }
    #pragma unroll
    for (int m = 1; m < 16; m <<= 1)
        #pragma unroll
        for (int mi = 0; mi < 4; ++mi)
            #pragma unroll
            for (int j = 0; j < 4; ++j)
                rsum[mi][j] += __shfl_xor(rsum[mi][j], m);
    if (lr == 0) {
        #pragma unroll
        for (int mi = 0; mi < 4; ++mi)
            #pragma unroll
            for (int j = 0; j < 4; ++j)
                psum[wave][mi * 16 + lg * 4 + j] = rsum[mi][j];
    }
    __syncthreads();
    if (tid < 64) {
        float n2 = psum[0][tid] + psum[1][tid] + psum[2][tid] + psum[3][tid];
        sinv[tid] = 1.f / fmaxf(sqrtf(n2), 1e-12f);
    }
    __syncthreads();

    // coalesced readback + store: 8 cols (16B bf16 / 32B f32) per thread-task
    constexpr int GPR  = DOUT / 8;           // col groups per row
    constexpr int ITER = 64 * GPR / 256;     // 4 (DOUT=128) or 2 (DOUT=64)
    #pragma unroll
    for (int i = 0; i < ITER; ++i) {
        int lin = i * 256 + tid;
        int row = lin / GPR, g = lin % GPR;
        int t = t0 + row;
        if (t < T) {
            float inv = sinv[row];
            float4 z0 = *(float4*)&smF[row * FSTR + g * 8];
            float4 z1 = *(float4*)&smF[row * FSTR + g * 8 + 4];
            float o0 = z0.x * inv, o1 = z0.y * inv, o2 = z0.z * inv, o3 = z0.w * inv;
            float o4 = z1.x * inv, o5 = z1.y * inv, o6 = z1.z * inv, o7 = z1.w * inv;
            short8 ob = {(short)f2bf(o0), (short)f2bf(o1), (short)f2bf(o2), (short)f2bf(o3),
                         (short)f2bf(o4), (short)f2bf(o5), (short)f2bf(o6), (short)f2bf(o7)};
            *(short8*)&outb[(size_t)t * DOUT + g * 8] = ob;
            if (WRITE_F32) {
                *(float4*)&outf[(size_t)t * DOUT + g * 8]     = (float4){o0, o1, o2, o3};
                *(float4*)&outf[(size_t)t * DOUT + g * 8 + 4] = (float4){o4, o5, o6, o7};
            }
        }
    }
}

// ---------------- cosine scores (bf16 embedding gathers) ----------------
// 8 lanes per pair (8 x ushort8 = 64 dims, 16B/lane)
__global__ __launch_bounds__(256) void score_kernel(const u16* __restrict__ hu,
                                                    const u16* __restrict__ hi,
                                                    const int* __restrict__ pu,
                                                    const int* __restrict__ pi,
                                                    float* __restrict__ out, int P) {
    int g = threadIdx.x >> 3, l = threadIdx.x & 7;
    int p = blockIdx.x * 32 + g;
    if (p >= P) return;
    int u = pu[p], it = pi[p];
    short8 a = *(const short8*)&hu[(size_t)u * 64 + (l << 3)];
    short8 b = *(const short8*)&hi[(size_t)it * 64 + (l << 3)];
    float d = 0.f, na = 0.f, nb = 0.f;
    #pragma unroll
    for (int q = 0; q < 8; ++q) {
        float x = bf2f((u16)a[q]), y = bf2f((u16)b[q]);
        d  = fmaf(x, y, d);
        na = fmaf(x, x, na);
        nb = fmaf(y, y, nb);
    }
    #pragma unroll
    for (int m = 1; m < 8; m <<= 1) {
        d  += __shfl_xor(d, m);
        na += __shfl_xor(na, m);
        nb += __shfl_xor(nb, m);
    }
    if (l == 0) out[p] = d / (fmaxf(sqrtf(na), 1e-12f) * fmaxf(sqrtf(nb), 1e-12f));
}

// ---------------- host ----------------

extern "C" void kernel_launch(void* const* d_in, const int* in_sizes, int n_in,
                              void* d_out, int out_size, void* d_ws, size_t ws_size,
                              hipStream_t stream) {
    const float* h_user = (const float*)d_in[0];
    const float* h_item = (const float*)d_in[1];
    const float* Wn01   = (const float*)d_in[2];
    const float* bn01   = (const float*)d_in[3];
    const float* Ws01   = (const float*)d_in[4];
    const float* bs01   = (const float*)d_in[5];
    const float* Wn2    = (const float*)d_in[6];
    const float* bn2    = (const float*)d_in[7];
    const float* Ws2    = (const float*)d_in[8];
    const float* bs2    = (const float*)d_in[9];
    const int* u2i_src  = (const int*)d_in[10];
    const int* u2i_dst  = (const int*)d_in[11];
    const int* i2u_src  = (const int*)d_in[12];
    const int* i2u_dst  = (const int*)d_in[13];
    const int* pos_u    = (const int*)d_in[14];
    const int* pos_i    = (const int*)d_in[15];
    const int* neg_u    = (const int*)d_in[16];
    const int* neg_i    = (const int*)d_in[17];

    float* out = (float*)d_out;
    float* out_hu = out;                       // [NU,64]
    float* out_hi = out + (size_t)NU * 64;     // [NI,64]
    float* out_pos = out + (size_t)NU * 64 + (size_t)NI * 64;
    float* out_neg = out_pos + NP;

    // workspace layout
    char* ws = (char*)d_ws;
    size_t off = 0;
    auto alloc = [&](size_t bytes) -> void* {
        void* p = ws + off;
        off = (off + bytes + 255) & ~(size_t)255;
        return p;
    };
    u16* hu0b = (u16*)alloc((size_t)NU * 128 * 2);   // bf16 copies of inputs
    u16* hi0b = (u16*)alloc((size_t)NI * 128 * 2);
    u16* hu_b = (u16*)alloc((size_t)NU * 128 * 2);   // layer intermediates (bf16)
    u16* hi_b = (u16*)alloc((size_t)NI * 128 * 2);
    u16* hu_a = (u16*)alloc((size_t)NU * 128 * 2);
    u16* hi_a = (u16*)alloc((size_t)NI * 128 * 2);
    u16* aggb = (u16*)alloc((size_t)NU * 128 * 2);   // agg output (bf16)
    u16* hu2b = (u16*)alloc((size_t)NU * 64 * 2);    // final embeddings (bf16, scores)
    u16* hi2b = (u16*)alloc((size_t)NI * 64 * 2);
    u16* wt_l0_i = (u16*)alloc((size_t)128 * 256 * 2);  // transposed bf16 weights
    u16* wt_l0_u = (u16*)alloc((size_t)128 * 256 * 2);
    u16* wt_l1_i = (u16*)alloc((size_t)128 * 256 * 2);
    u16* wt_l1_u = (u16*)alloc((size_t)128 * 256 * 2);
    u16* wt_l2_i = (u16*)alloc((size_t)64 * 256 * 2);
    u16* wt_l2_u = (u16*)alloc((size_t)64 * 256 * 2);
    int* csr_u2i = (int*)alloc((size_t)NE * 4);
    int* csr_i2u = (int*)alloc((size_t)NE * 4);
    int* rs_i   = (int*)alloc((size_t)(NI + 1) * 4);
    int* rs_u   = (int*)alloc((size_t)(NU + 1) * 4);
    int* deg    = (int*)alloc((size_t)NU * 4);
    int* cursor = (int*)alloc((size_t)NU * 4);
    int* bsum   = (int*)alloc(1024 * 4);
    (void)ws_size; (void)in_sizes; (void)n_in; (void)out_size;

    const int eblocks = (NE + 255) / 256;

    // ---- bf16 copies of input features + transposed bf16 weights ----
    cvt_kernel<<<(NU * 128 / 8 + 255) / 256, 256, 0, stream>>>(h_user, hu0b, NU * 128 / 8);
    cvt_kernel<<<(NI * 128 / 8 + 255) / 256, 256, 0, stream>>>(h_item, hi0b, NI * 128 / 8);
    wtrans_kernel<<<128, 128, 0, stream>>>(Wn01 + 0,     Ws01 + 0,     wt_l0_i, 128);
    wtrans_kernel<<<128, 128, 0, stream>>>(Wn01 + 16384, Ws01 + 16384, wt_l0_u, 128);
    wtrans_kernel<<<128, 128, 0, stream>>>(Wn01 + 32768, Ws01 + 32768, wt_l1_i, 128);
    wtrans_kernel<<<128, 128, 0, stream>>>(Wn01 + 49152, Ws01 + 49152, wt_l1_u, 128);
    wtrans_kernel<<<64, 128, 0, stream>>>(Wn2 + 0,    Ws2 + 0,    wt_l2_i, 64);
    wtrans_kernel<<<64, 128, 0, stream>>>(Wn2 + 8192, Ws2 + 8192, wt_l2_u, 64);

    // ---- CSR for u2i (dst = items) ----
    {
        hipMemsetAsync(deg, 0, (size_t)NI * 4, stream);
        hist_kernel<<<eblocks, 256, 0, stream>>>(u2i_dst, deg, NE);
        int nb = (NI + 1023) / 1024;
        scan_local_kernel<<<nb, 1024, 0, stream>>>(deg, rs_i, bsum, NI);
        scan_bsum_kernel<<<1, 1024, 0, stream>>>(bsum, nb);
        scan_finalize_kernel<<<nb, 1024, 0, stream>>>(rs_i, bsum, cursor, NI, NE);
        fill_kernel<<<eblocks * 8, 256, 0, stream>>>(u2i_src, u2i_dst, cursor,
                                                     csr_u2i, NE, NI);
    }
    // ---- CSR for i2u (dst = users) ----
    {
        hipMemsetAsync(deg, 0, (size_t)NU * 4, stream);
        hist_kernel<<<eblocks, 256, 0, stream>>>(i2u_dst, deg, NE);
        int nb = (NU + 1023) / 1024;
        scan_local_kernel<<<nb, 1024, 0, stream>>>(deg, rs_u, bsum, NU);
        scan_bsum_kernel<<<1, 1024, 0, stream>>>(bsum, nb);
        scan_finalize_kernel<<<nb, 1024, 0, stream>>>(rs_u, bsum, cursor, NU, NE);
        fill_kernel<<<eblocks * 8, 256, 0, stream>>>(i2u_src, i2u_dst, cursor,
                                                     csr_i2u, NE, NU);
    }

    const int gi = (NI + 3) / 4, gu = (NU + 3) / 4;          // agg grids
    const int ci = (NI + 63) / 64, cu = (NU + 63) / 64;      // conv grids (64-row tiles)

    // ---- layer 0 ----
    agg_kernel<<<gi, 256, 0, stream>>>(hu0b, rs_i, csr_u2i, aggb, NI);
    conv_mfma_kernel<128, false><<<ci, 256, 0, stream>>>(aggb, hi0b, wt_l0_i,
                                                         bn01 + 0, bs01 + 0,
                                                         nullptr, hi_b, NI);
    agg_kernel<<<gu, 256, 0, stream>>>(hi0b, rs_u, csr_i2u, aggb, NU);
    conv_mfma_kernel<128, false><<<cu, 256, 0, stream>>>(aggb, hu0b, wt_l0_u,
                                                         bn01 + 128, bs01 + 128,
                                                         nullptr, hu_b, NU);
    // ---- layer 1 ----
    agg_kernel<<<gi, 256, 0, stream>>>(hu_b, rs_i, csr_u2i, aggb, NI);
    conv_mfma_kernel<128, false><<<ci, 256, 0, stream>>>(aggb, hi_b, wt_l1_i,
                                                         bn01 + 256, bs01 + 256,
                                                         nullptr, hi_a, NI);
    agg_kernel<<<gu, 256, 0, stream>>>(hi_b, rs_u, csr_i2u, aggb, NU);
    conv_mfma_kernel<128, false><<<cu, 256, 0, stream>>>(aggb, hu_b, wt_l1_u,
                                                         bn01 + 384, bs01 + 384,
                                                         nullptr, hu_a, NU);
    // ---- layer 2 (writes d_out embeddings f32 + bf16 copy for scores) ----
    agg_kernel<<<gi, 256, 0, stream>>>(hu_a, rs_i, csr_u2i, aggb, NI);
    conv_mfma_kernel<64, true><<<ci, 256, 0, stream>>>(aggb, hi_a, wt_l2_i,
                                                       bn2 + 0, bs2 + 0,
                                                       out_hi, hi2b, NI);
    agg_kernel<<<gu, 256, 0, stream>>>(hi_a, rs_u, csr_i2u, aggb, NU);
    conv_mfma_kernel<64, true><<<cu, 256, 0, stream>>>(aggb, hu_a, wt_l2_u,
                                                       bn2 + 64, bs2 + 64,
                                                       out_hu, hu2b, NU);

    // ---- cosine scores ----
    const int pblocks = (NP + 31) / 32;
    score_kernel<<<pblocks, 256, 0, stream>>>(hu2b, hi2b, pos_u, pos_i, out_pos, NP);
    score_kernel<<<pblocks, 256, 0, stream>>>(hu2b, hi2b, neg_u, neg_i, out_neg, NP);
}